// Round 1
// baseline (2738.785 us; speedup 1.0000x reference)
//
#include <hip/hip_runtime.h>
#include <hip/hip_bf16.h>
#include <math.h>

#define NN 16
#define CC 64
#define TT_ 634
#define VV 26
#define TV 16484      // TT_*VV
#define KK 3
#define OO 192        // KK*CC
#define TKK 9
#define NCLS 60
#define NAE 4
#define EPS 1e-5f

// ---------------------------------------------------------------------------
// K1: y = relu(bnA( einsum('nkctv,kvw->nctw', (W@h + b).reshape, A*M) ))
// one block per (n, t); LDS: h-slice [64][32], y1 [192][28], A*M [3][26][32]
// ---------------------------------------------------------------------------
__global__ __launch_bounds__(256) void k_sgc_graph(
    const float* __restrict__ hin, const float* __restrict__ W,
    const float* __restrict__ Wb, const float* __restrict__ Ap,
    const float* __restrict__ Mp, const float* __restrict__ bg,
    const float* __restrict__ bb, const float* __restrict__ bm,
    const float* __restrict__ bv, float* __restrict__ hout)
{
  const int tid = threadIdx.x;
  const int n = blockIdx.x / TT_, t = blockIdx.x % TT_;
  __shared__ float sh[CC * 32];        // [c][v pad 32]
  __shared__ float sy1[OO * 28];       // [o][v pad 28]
  __shared__ float sAM[KK * VV * 32];  // [k][vr][w pad 32]
  const float* hb = hin + (size_t)n * CC * TV + (size_t)t * VV;
  for (int i = tid; i < CC * 32; i += 256) {
    const int c = i >> 5, v = i & 31;
    sh[i] = (v < VV) ? hb[(size_t)c * TV + v] : 0.f;
  }
  for (int i = tid; i < KK * VV * VV; i += 256) {
    const int k = i / (VV * VV), r = i - k * VV * VV;
    const int vr = r / VV, w = r - vr * VV;
    sAM[(k * VV + vr) * 32 + w] = Ap[i] * Mp[i];
  }
  __syncthreads();
  // phase 1: y1[o][v] = sum_c W[o,c] h[c,v] + Wb[o]
  {
    const int v = tid & 31, osub = tid >> 5;
    for (int oi = 0; oi < OO / 8; ++oi) {
      const int o = oi * 8 + osub;
      const float* wr = W + o * CC;
      float acc = 0.f;
      #pragma unroll
      for (int c = 0; c < CC; c += 4) {
        const float4 w4 = *(const float4*)(wr + c);
        acc = fmaf(w4.x, sh[c * 32 + v], acc);
        acc = fmaf(w4.y, sh[(c + 1) * 32 + v], acc);
        acc = fmaf(w4.z, sh[(c + 2) * 32 + v], acc);
        acc = fmaf(w4.w, sh[(c + 3) * 32 + v], acc);
      }
      if (v < VV) sy1[o * 28 + v] = acc + Wb[o];
    }
  }
  __syncthreads();
  // phase 2: y2[c][w] = sum_{k,v} y1[k*64+c][v] * AM[k][v][w]; BN+ReLU; store
  {
    const int w = tid & 31, cg = tid >> 5;
    const int c0 = cg * 8;
    if (w < VV) {
      float acc[8] = {0, 0, 0, 0, 0, 0, 0, 0};
      for (int k = 0; k < KK; ++k) {
        for (int v = 0; v < VV; ++v) {
          const float p = sAM[(k * VV + v) * 32 + w];
          const float* yr = sy1 + (k * CC + c0) * 28 + v;
          #pragma unroll
          for (int j = 0; j < 8; ++j) acc[j] = fmaf(yr[j * 28], p, acc[j]);
        }
      }
      float* ob = hout + (size_t)n * CC * TV + (size_t)c0 * TV + (size_t)t * VV + w;
      #pragma unroll
      for (int j = 0; j < 8; ++j) {
        const int c = c0 + j;
        const float s = bg[c] * rsqrtf(bv[c] + EPS);
        const float off = bb[c] - bm[c] * s;
        ob[(size_t)j * TV] = fmaxf(fmaf(acc[j], s, off), 0.f);
      }
    }
  }
}

// ---------------------------------------------------------------------------
// K2: temporal conv (TK=9 over t, same-pad) + bias + bnB + relu
// Flat f = t*26+v; shift by (dt-4)*26 == t-shift (v preserved).
// Block: (n, 64-wide f tile), all 64 out channels; 8 input-channel chunks.
// Thread: 4c x 4f register tile. LDS: in [8][272], w [72][68 pad].
// ---------------------------------------------------------------------------
__global__ __launch_bounds__(256) void k_tconv(
    const float* __restrict__ xin, const float* __restrict__ wt,
    const float* __restrict__ wb, const float* __restrict__ bg,
    const float* __restrict__ bb, const float* __restrict__ bm,
    const float* __restrict__ bv, float* __restrict__ xout)
{
  const int tid = threadIdx.x;
  const int NF = (TV + 63) / 64;  // 258
  const int n = blockIdx.x / NF, ft = blockIdx.x % NF;
  const int f0 = ft * 64;
  __shared__ float si[8 * 272];
  __shared__ float sw[72 * 68];
  const float* xb = xin + (size_t)n * CC * TV;
  const int cg = tid >> 4, fg = tid & 15;
  const int c0 = cg * 4, fl0 = fg * 4;
  float acc[4][4] = {};
  for (int cc = 0; cc < 8; ++cc) {
    for (int i = tid; i < 8 * 272; i += 256) {
      const int cl = i / 272, j = i - cl * 272;
      const int fglob = f0 - 104 + j;
      si[i] = (fglob >= 0 && fglob < TV) ? xb[(size_t)(cc * 8 + cl) * TV + fglob] : 0.f;
    }
    for (int i = tid; i < 64 * 72; i += 256) {
      const int c = i / 72, q = i - c * 72;   // q = cl*9 + dt
      sw[q * 68 + c] = wt[c * 576 + cc * 72 + q];
    }
    __syncthreads();
    #pragma unroll
    for (int cl = 0; cl < 8; ++cl) {
      #pragma unroll
      for (int dt = 0; dt < TKK; ++dt) {
        const float4 w4 = *(const float4*)&sw[(cl * 9 + dt) * 68 + c0];
        const float* ip = &si[cl * 272 + fl0 + dt * 26];
        const float2 i0 = *(const float2*)ip;
        const float2 i1 = *(const float2*)(ip + 2);
        const float wv[4] = {w4.x, w4.y, w4.z, w4.w};
        const float in4[4] = {i0.x, i0.y, i1.x, i1.y};
        #pragma unroll
        for (int a = 0; a < 4; ++a)
          #pragma unroll
          for (int b = 0; b < 4; ++b)
            acc[a][b] = fmaf(wv[a], in4[b], acc[a][b]);
      }
    }
    __syncthreads();
  }
  #pragma unroll
  for (int a = 0; a < 4; ++a) {
    const int c = c0 + a;
    const float s = bg[c] * rsqrtf(bv[c] + EPS);
    const float off = fmaf(wb[c] - bm[c], s, bb[c]);
    const int f = f0 + fl0;
    float* op = xout + (size_t)n * CC * TV + (size_t)c * TV + f;
    float4 o4;
    o4.x = fmaxf(fmaf(acc[a][0], s, off), 0.f);
    o4.y = fmaxf(fmaf(acc[a][1], s, off), 0.f);
    o4.z = fmaxf(fmaf(acc[a][2], s, off), 0.f);
    o4.w = fmaxf(fmaf(acc[a][3], s, off), 0.f);
    if (f + 3 < TV) {
      *(float4*)op = o4;
    } else {
      const float vals[4] = {o4.x, o4.y, o4.z, o4.w};
      for (int b = 0; b < 4; ++b)
        if (f + b < TV) op[b] = vals[b];
    }
  }
}

// ---------------------------------------------------------------------------
// K3a: pooled[n,c] = mean_{t,v} h ; hmeanv[n,c,v] = mean_t h. block per (n,c)
// ---------------------------------------------------------------------------
__global__ __launch_bounds__(256) void k_pool(
    const float* __restrict__ h, float* __restrict__ pooled,
    float* __restrict__ hmeanv)
{
  const int tid = threadIdx.x;
  const int bid = blockIdx.x;  // n*64 + c
  const float* row = h + (size_t)bid * TV;
  __shared__ float part[9 * VV];
  if (tid < 9 * VV) {
    const int tt = tid / VV, v = tid - tt * VV;
    float s = 0.f;
    for (int t = tt; t < TT_; t += 9) s += row[t * VV + v];
    part[tid] = s;
  }
  __syncthreads();
  if (tid < VV) {
    float tot = 0.f;
    #pragma unroll
    for (int j = 0; j < 9; ++j) tot += part[j * VV + tid];
    hmeanv[(size_t)bid * VV + tid] = tot / (float)TT_;
    part[tid] = tot;
  }
  __syncthreads();
  if (tid == 0) {
    float tot = 0.f;
    for (int v = 0; v < VV; ++v) tot += part[v];
    pooled[bid] = tot / (float)TV;
  }
}

// ---------------------------------------------------------------------------
// K3b: per-n head: cls output + edge attention (mean-T commutes with linears)
// ---------------------------------------------------------------------------
__global__ __launch_bounds__(256) void k_head_edge(
    const float* __restrict__ pooled, const float* __restrict__ hmeanv,
    const float* __restrict__ fcw, const float* __restrict__ fcb,
    const float* __restrict__ ag, const float* __restrict__ ab,
    const float* __restrict__ am, const float* __restrict__ av,
    const float* __restrict__ attw, const float* __restrict__ edgew,
    const float* __restrict__ eg, const float* __restrict__ eb,
    const float* __restrict__ em, const float* __restrict__ ev,
    float* __restrict__ dout)
{
  const int tid = threadIdx.x;
  const int n = blockIdx.x;
  __shared__ float sbnm[CC * VV];
  __shared__ float sxam[NCLS * VV];
  __shared__ float spool[CC];
  for (int i = tid; i < CC * VV; i += 256) {
    const int c = i / VV;
    const float s = ag[c] * rsqrtf(av[c] + EPS);
    const float off = ab[c] - am[c] * s;
    sbnm[i] = fmaf(hmeanv[(size_t)(n * CC) * VV + i], s, off);
  }
  if (tid < CC) spool[tid] = pooled[n * CC + tid];
  __syncthreads();
  for (int i = tid; i < NCLS * VV; i += 256) {
    const int o = i / VV, v = i - o * VV;
    float a = 0.f;
    for (int c = 0; c < CC; ++c) a = fmaf(attw[o * CC + c], sbnm[c * VV + v], a);
    sxam[i] = a;
  }
  if (tid < NCLS) {
    float a = fcb[tid];
    for (int c = 0; c < CC; ++c) a = fmaf(spool[c], fcw[tid * CC + c], a);
    dout[n * NCLS + tid] = a;
  }
  __syncthreads();
  for (int i = tid; i < NAE * VV * VV; i += 256) {
    const int j = i / VV, v = i - j * VV;
    float a = 0.f;
    for (int o = 0; o < NCLS; ++o) a = fmaf(edgew[j * NCLS + o], sxam[o * VV + v], a);
    const float s = eg[j] * rsqrtf(ev[j] + EPS);
    const float val = tanhf(fmaf(a - em[j], s, eb[j]));
    dout[NN * NCLS + (size_t)NN * TV + (size_t)n * NAE * VV * VV + i] = fmaxf(val, 0.f);
  }
}

// ---------------------------------------------------------------------------
// K3c: att_node = sigmoid(bn_node( h . (s_c * sum_o nodeconv*attconv) + b0 ))
// ---------------------------------------------------------------------------
__global__ __launch_bounds__(256) void k_node(
    const float* __restrict__ h,
    const float* __restrict__ ag, const float* __restrict__ ab,
    const float* __restrict__ am, const float* __restrict__ av,
    const float* __restrict__ attw, const float* __restrict__ nodew,
    const float* __restrict__ ng, const float* __restrict__ nb,
    const float* __restrict__ nm, const float* __restrict__ nv,
    float* __restrict__ dout)
{
  const int tid = threadIdx.x;
  __shared__ float ac[CC];
  __shared__ float tmp[CC];
  if (tid < CC) {
    float nc = 0.f;
    for (int o = 0; o < NCLS; ++o) nc = fmaf(nodew[o], attw[o * CC + tid], nc);
    const float s = ag[tid] * rsqrtf(av[tid] + EPS);
    const float off = ab[tid] - am[tid] * s;
    ac[tid] = nc * s;
    tmp[tid] = nc * off;
  }
  __syncthreads();
  if (tid == 0) {
    float b = 0.f;
    for (int c = 0; c < CC; ++c) b += tmp[c];
    tmp[0] = b;
  }
  __syncthreads();
  const float b0 = tmp[0];
  const size_t i = (size_t)blockIdx.x * 256 + tid;
  if (i < (size_t)NN * TV) {
    const int n = (int)(i / TV), f = (int)(i - (size_t)n * TV);
    const float* hb = h + (size_t)n * CC * TV + f;
    float xsum = b0;
    #pragma unroll 8
    for (int c = 0; c < CC; ++c) xsum = fmaf(hb[(size_t)c * TV], ac[c], xsum);
    const float s = ng[0] * rsqrtf(nv[0] + EPS);
    const float y = fmaf(xsum - nm[0], s, nb[0]);
    dout[NN * NCLS + i] = 1.f / (1.f + expf(-y));
  }
}

// ---------------------------------------------------------------------------
extern "C" void kernel_launch(void* const* d_in, const int* in_sizes, int n_in,
                              void* d_out, int out_size, void* d_ws, size_t ws_size,
                              hipStream_t stream) {
  const float* x        = (const float*)d_in[0];
  const float* A        = (const float*)d_in[1];
  const float* sgc_w    = (const float*)d_in[2];
  const float* sgc_b    = (const float*)d_in[3];
  const float* M        = (const float*)d_in[4];
  const float* bnA_g    = (const float*)d_in[5];
  const float* bnA_b    = (const float*)d_in[6];
  const float* bnA_m    = (const float*)d_in[7];
  const float* bnA_v    = (const float*)d_in[8];
  const float* tconv_w  = (const float*)d_in[9];
  const float* tconv_b  = (const float*)d_in[10];
  const float* bnB_g    = (const float*)d_in[11];
  const float* bnB_b    = (const float*)d_in[12];
  const float* bnB_m    = (const float*)d_in[13];
  const float* bnB_v    = (const float*)d_in[14];
  const float* fc_w     = (const float*)d_in[15];
  const float* fc_b     = (const float*)d_in[16];
  const float* attbn_g  = (const float*)d_in[17];
  const float* attbn_b  = (const float*)d_in[18];
  const float* attbn_m  = (const float*)d_in[19];
  const float* attbn_v  = (const float*)d_in[20];
  // d_in[21..34]: transformer branch params — dead code in the reference.
  const float* attconv_w  = (const float*)d_in[35];
  const float* nodeconv_w = (const float*)d_in[36];
  const float* nodebn_g   = (const float*)d_in[37];
  const float* nodebn_b   = (const float*)d_in[38];
  const float* nodebn_m   = (const float*)d_in[39];
  const float* nodebn_v   = (const float*)d_in[40];
  const float* edgeconv_w = (const float*)d_in[41];
  const float* edgebn_g   = (const float*)d_in[42];
  const float* edgebn_b   = (const float*)d_in[43];
  const float* edgebn_m   = (const float*)d_in[44];
  const float* edgebn_v   = (const float*)d_in[45];

  // workspace: two ping-pong activation buffers + small head scratch
  float* bufA   = (float*)d_ws;                       // 16*64*16484 floats
  float* bufB   = bufA + (size_t)NN * CC * TV;        // 16*64*16484 floats
  float* pooled = bufB + (size_t)NN * CC * TV;        // 1024
  float* hmeanv = pooled + NN * CC;                   // 16*64*26
  float* out = (float*)d_out;

  const int NF = (TV + 63) / 64;
  for (int i = 0; i < 3; ++i) {
    const float* src = (i == 0) ? x : bufB;
    k_sgc_graph<<<NN * TT_, 256, 0, stream>>>(
        src, sgc_w + (size_t)i * OO * CC, sgc_b + i * OO, A,
        M + (size_t)i * KK * VV * VV, bnA_g + i * CC, bnA_b + i * CC,
        bnA_m + i * CC, bnA_v + i * CC, bufA);
    k_tconv<<<NN * NF, 256, 0, stream>>>(
        bufA, tconv_w + (size_t)i * CC * CC * TKK, tconv_b + i * CC,
        bnB_g + i * CC, bnB_b + i * CC, bnB_m + i * CC, bnB_v + i * CC, bufB);
  }
  k_pool<<<NN * CC, 256, 0, stream>>>(bufB, pooled, hmeanv);
  k_head_edge<<<NN, 256, 0, stream>>>(pooled, hmeanv, fc_w, fc_b,
      attbn_g, attbn_b, attbn_m, attbn_v, attconv_w, edgeconv_w,
      edgebn_g, edgebn_b, edgebn_m, edgebn_v, out);
  k_node<<<((size_t)NN * TV + 255) / 256, 256, 0, stream>>>(
      bufB, attbn_g, attbn_b, attbn_m, attbn_v, attconv_w, nodeconv_w,
      nodebn_g, nodebn_b, nodebn_m, nodebn_v, out);
}

// Round 2
// 2045.650 us; speedup vs baseline: 1.3388x; 1.3388x over previous
//
#include <hip/hip_runtime.h>
#include <hip/hip_bf16.h>
#include <math.h>

#define NN 16
#define CC 64
#define TT_ 634
#define VV 26
#define TV 16484      // TT_*VV
#define KK 3
#define OO 192        // KK*CC
#define TKK 9
#define NCLS 60
#define NAE 4
#define EPS 1e-5f

static __device__ __forceinline__ float bf2f(unsigned int u) {
  union { unsigned int i; float f; } v; v.i = u << 16; return v.f;
}
static __device__ __forceinline__ unsigned int f2bf(float x) {
  union { float f; unsigned int i; } v; v.f = x;
  unsigned int r = v.i + 0x7fffu + ((v.i >> 16) & 1u);
  return r >> 16;
}

// ---------------------------------------------------------------------------
// S1: y1[n][o][f] (bf16) = sum_c W[o][c] * h[n][c][f] + Wb[o]
// GEMM: block tile 64(o) x 128(f), K=64 entirely in LDS. thread tile 8o x 4f.
// grid = ncount * KK * NFT
// ---------------------------------------------------------------------------
__global__ __launch_bounds__(256) void k_sgc_pw(
    const float* __restrict__ hin,          // [ncount][64][TV]
    const float* __restrict__ W,            // [192][64]
    const float* __restrict__ Wb,           // [192]
    unsigned short* __restrict__ y1,        // [ncount][192][TV] bf16
    int ncount)
{
  const int NFT = (TV + 127) >> 7;  // 129
  const int tid = threadIdx.x;
  int bid = blockIdx.x;
  const int ft = bid % NFT; bid /= NFT;
  const int ot = bid % KK;  bid /= KK;
  const int n  = bid;
  const int f0 = ft << 7;
  const int o0 = ot << 6;
  __shared__ float sW[CC][68];     // [c(k)][o-tile 64, pad->68]
  __shared__ float sH[CC][128];    // [c(k)][f-tile]
  for (int l = tid; l < CC * CC; l += 256) {
    const int o = l >> 6, c = l & 63;
    sW[c][o] = W[(size_t)(o0 + o) * CC + c];
  }
  const float* hb = hin + (size_t)n * CC * TV;
  for (int l = tid; l < CC * 128; l += 256) {
    const int c = l >> 7, f = l & 127;
    const int fg = f0 + f;
    sH[c][f] = (fg < TV) ? hb[(size_t)c * TV + fg] : 0.f;
  }
  __syncthreads();
  const int ogrp = tid >> 5;       // 0..7
  const int fgrp = tid & 31;       // 0..31
  const int ol = ogrp << 3, fl = fgrp << 2;
  float acc[8][4] = {};
  #pragma unroll 4
  for (int k = 0; k < CC; ++k) {
    const float4 w0 = *(const float4*)&sW[k][ol];
    const float4 w1 = *(const float4*)&sW[k][ol + 4];
    const float4 hv = *(const float4*)&sH[k][fl];
    const float wv[8] = {w0.x, w0.y, w0.z, w0.w, w1.x, w1.y, w1.z, w1.w};
    const float hf[4] = {hv.x, hv.y, hv.z, hv.w};
    #pragma unroll
    for (int a = 0; a < 8; ++a)
      #pragma unroll
      for (int b = 0; b < 4; ++b)
        acc[a][b] = fmaf(wv[a], hf[b], acc[a][b]);
  }
  const int fg = f0 + fl;
  if (fg < TV) {   // TV % 4 == 0 -> quad fully valid or fully out
    #pragma unroll
    for (int a = 0; a < 8; ++a) {
      const int o = o0 + ol + a;
      const float bias = Wb[o];
      uint2 pk;
      pk.x = f2bf(acc[a][0] + bias) | (f2bf(acc[a][1] + bias) << 16);
      pk.y = f2bf(acc[a][2] + bias) | (f2bf(acc[a][3] + bias) << 16);
      *(uint2*)(y1 + ((size_t)n * OO + o) * TV + fg) = pk;
    }
  }
}

// ---------------------------------------------------------------------------
// S2: h1[n][c][t*26+w] = relu(bn( sum_{k,v} y1[n][k*64+c][t*26+v]*AM[k][v][w] ))
// block: (n, t-tile of 4). thread: (t_loc, cgrp, wq) -> 8c x 4w register tile.
// LDS: sy[k][t][v][c pad72] bf16 (c contiguous -> b128 frag reads), sAM f32.
// ---------------------------------------------------------------------------
__global__ __launch_bounds__(256) void k_sgc_graph2(
    const unsigned short* __restrict__ y1,  // [ncount][192][TV] bf16
    const float* __restrict__ Ap, const float* __restrict__ Mp,
    const float* __restrict__ bg, const float* __restrict__ bb,
    const float* __restrict__ bm, const float* __restrict__ bv,
    float* __restrict__ hout,               // [ncount][64][TV]
    int ncount)
{
  const int NTT = (TT_ + 3) >> 2;  // 159
  const int tid = threadIdx.x;
  const int tt = blockIdx.x % NTT;
  const int n  = blockIdx.x / NTT;
  const int t0 = tt << 2;
  const int f0 = t0 * VV;
  __shared__ unsigned short sy[KK][4][VV][72];  // bf16, c fast
  __shared__ float sAM[KK][VV][28];
  for (int l = tid; l < KK * VV * 28; l += 256) {
    const int k = l / (VV * 28), r = l % (VV * 28);
    const int v = r / 28, w = r % 28;
    sAM[k][v][w] = (w < VV) ? Ap[(k * VV + v) * VV + w] * Mp[(k * VV + v) * VV + w]
                            : 0.f;
  }
  const unsigned short* yb = y1 + (size_t)n * OO * TV;
  for (int l = tid; l < OO * 52; l += 256) {   // 2-element (4B) units
    const int o = l / 52, j = l % 52;
    const int f = f0 + 2 * j;
    unsigned int val = 0;
    if (f + 2 <= TV) val = *(const unsigned int*)(yb + (size_t)o * TV + f);
    const int k = o >> 6, c = o & 63;
    const int floc = 2 * j;
    const int tl = floc / VV, v = floc % VV;   // v even <= 24: pair same t
    sy[k][tl][v][c]     = (unsigned short)(val & 0xffffu);
    sy[k][tl][v + 1][c] = (unsigned short)(val >> 16);
  }
  __syncthreads();
  const int tl = tid >> 6;          // 0..3
  const int cg = (tid >> 3) & 7;    // 0..7
  const int wq = tid & 7;           // 0..7, wq==7 idle
  const int c0 = cg << 3, w0 = wq << 2;
  float acc[8][4] = {};
  if (wq < 7) {
    for (int k = 0; k < KK; ++k) {
      #pragma unroll 2
      for (int v = 0; v < VV; ++v) {
        const float4 am = *(const float4*)&sAM[k][v][w0];
        const uint4 yv = *(const uint4*)&sy[k][tl][v][c0];
        float yf[8];
        yf[0] = bf2f(yv.x & 0xffffu); yf[1] = bf2f(yv.x >> 16);
        yf[2] = bf2f(yv.y & 0xffffu); yf[3] = bf2f(yv.y >> 16);
        yf[4] = bf2f(yv.z & 0xffffu); yf[5] = bf2f(yv.z >> 16);
        yf[6] = bf2f(yv.w & 0xffffu); yf[7] = bf2f(yv.w >> 16);
        const float amf[4] = {am.x, am.y, am.z, am.w};
        #pragma unroll
        for (int a = 0; a < 8; ++a)
          #pragma unroll
          for (int b = 0; b < 4; ++b)
            acc[a][b] = fmaf(yf[a], amf[b], acc[a][b]);
      }
    }
  }
  const int t = t0 + tl;
  if (wq < 7 && t < TT_) {
    #pragma unroll
    for (int a = 0; a < 8; ++a) {
      const int c = c0 + a;
      const float s = bg[c] * rsqrtf(bv[c] + EPS);
      const float off = bb[c] - bm[c] * s;
      float* ob = hout + ((size_t)n * CC + c) * TV + t * VV + w0;
      if (w0 + 4 <= VV) {
        float2 p0, p1;
        p0.x = fmaxf(fmaf(acc[a][0], s, off), 0.f);
        p0.y = fmaxf(fmaf(acc[a][1], s, off), 0.f);
        p1.x = fmaxf(fmaf(acc[a][2], s, off), 0.f);
        p1.y = fmaxf(fmaf(acc[a][3], s, off), 0.f);
        *(float2*)ob = p0;
        *(float2*)(ob + 2) = p1;
      } else {
        #pragma unroll
        for (int b = 0; b < 4; ++b)
          if (w0 + b < VV) ob[b] = fmaxf(fmaf(acc[a][b], s, off), 0.f);
      }
    }
  }
}

// ---------------------------------------------------------------------------
// K2: temporal conv (TK=9 over t, same-pad) + bias + bnB + relu  (unchanged)
// ---------------------------------------------------------------------------
__global__ __launch_bounds__(256) void k_tconv(
    const float* __restrict__ xin, const float* __restrict__ wt,
    const float* __restrict__ wb, const float* __restrict__ bg,
    const float* __restrict__ bb, const float* __restrict__ bm,
    const float* __restrict__ bv, float* __restrict__ xout)
{
  const int tid = threadIdx.x;
  const int NF = (TV + 63) / 64;  // 258
  const int n = blockIdx.x / NF, ft = blockIdx.x % NF;
  const int f0 = ft * 64;
  __shared__ float si[8 * 272];
  __shared__ float sw[72 * 68];
  const float* xb = xin + (size_t)n * CC * TV;
  const int cg = tid >> 4, fg = tid & 15;
  const int c0 = cg * 4, fl0 = fg * 4;
  float acc[4][4] = {};
  for (int cc = 0; cc < 8; ++cc) {
    for (int i = tid; i < 8 * 272; i += 256) {
      const int cl = i / 272, j = i - cl * 272;
      const int fglob = f0 - 104 + j;
      si[i] = (fglob >= 0 && fglob < TV) ? xb[(size_t)(cc * 8 + cl) * TV + fglob] : 0.f;
    }
    for (int i = tid; i < 64 * 72; i += 256) {
      const int c = i / 72, q = i - c * 72;   // q = cl*9 + dt
      sw[q * 68 + c] = wt[c * 576 + cc * 72 + q];
    }
    __syncthreads();
    #pragma unroll
    for (int cl = 0; cl < 8; ++cl) {
      #pragma unroll
      for (int dt = 0; dt < TKK; ++dt) {
        const float4 w4 = *(const float4*)&sw[(cl * 9 + dt) * 68 + c0];
        const float* ip = &si[cl * 272 + fl0 + dt * 26];
        const float2 i0 = *(const float2*)ip;
        const float2 i1 = *(const float2*)(ip + 2);
        const float wv[4] = {w4.x, w4.y, w4.z, w4.w};
        const float in4[4] = {i0.x, i0.y, i1.x, i1.y};
        #pragma unroll
        for (int a = 0; a < 4; ++a)
          #pragma unroll
          for (int b = 0; b < 4; ++b)
            acc[a][b] = fmaf(wv[a], in4[b], acc[a][b]);
      }
    }
    __syncthreads();
  }
  #pragma unroll
  for (int a = 0; a < 4; ++a) {
    const int c = c0 + a;
    const float s = bg[c] * rsqrtf(bv[c] + EPS);
    const float off = fmaf(wb[c] - bm[c], s, bb[c]);
    const int f = f0 + fl0;
    float* op = xout + (size_t)n * CC * TV + (size_t)c * TV + f;
    float4 o4;
    o4.x = fmaxf(fmaf(acc[a][0], s, off), 0.f);
    o4.y = fmaxf(fmaf(acc[a][1], s, off), 0.f);
    o4.z = fmaxf(fmaf(acc[a][2], s, off), 0.f);
    o4.w = fmaxf(fmaf(acc[a][3], s, off), 0.f);
    if (f + 3 < TV) {
      *(float4*)op = o4;
    } else {
      const float vals[4] = {o4.x, o4.y, o4.z, o4.w};
      for (int b = 0; b < 4; ++b)
        if (f + b < TV) op[b] = vals[b];
    }
  }
}

// ---------------------------------------------------------------------------
// K3a: pooled[n,c] = mean_{t,v} h ; hmeanv[n,c,v] = mean_t h  (unchanged)
// ---------------------------------------------------------------------------
__global__ __launch_bounds__(256) void k_pool(
    const float* __restrict__ h, float* __restrict__ pooled,
    float* __restrict__ hmeanv)
{
  const int tid = threadIdx.x;
  const int bid = blockIdx.x;  // n*64 + c
  const float* row = h + (size_t)bid * TV;
  __shared__ float part[9 * VV];
  if (tid < 9 * VV) {
    const int tt = tid / VV, v = tid - tt * VV;
    float s = 0.f;
    for (int t = tt; t < TT_; t += 9) s += row[t * VV + v];
    part[tid] = s;
  }
  __syncthreads();
  if (tid < VV) {
    float tot = 0.f;
    #pragma unroll
    for (int j = 0; j < 9; ++j) tot += part[j * VV + tid];
    hmeanv[(size_t)bid * VV + tid] = tot / (float)TT_;
    part[tid] = tot;
  }
  __syncthreads();
  if (tid == 0) {
    float tot = 0.f;
    for (int v = 0; v < VV; ++v) tot += part[v];
    pooled[bid] = tot / (float)TV;
  }
}

// ---------------------------------------------------------------------------
// K3b: per-n head: cls output + edge attention  (unchanged)
// ---------------------------------------------------------------------------
__global__ __launch_bounds__(256) void k_head_edge(
    const float* __restrict__ pooled, const float* __restrict__ hmeanv,
    const float* __restrict__ fcw, const float* __restrict__ fcb,
    const float* __restrict__ ag, const float* __restrict__ ab,
    const float* __restrict__ am, const float* __restrict__ av,
    const float* __restrict__ attw, const float* __restrict__ edgew,
    const float* __restrict__ eg, const float* __restrict__ eb,
    const float* __restrict__ em, const float* __restrict__ ev,
    float* __restrict__ dout)
{
  const int tid = threadIdx.x;
  const int n = blockIdx.x;
  __shared__ float sbnm[CC * VV];
  __shared__ float sxam[NCLS * VV];
  __shared__ float spool[CC];
  for (int i = tid; i < CC * VV; i += 256) {
    const int c = i / VV;
    const float s = ag[c] * rsqrtf(av[c] + EPS);
    const float off = ab[c] - am[c] * s;
    sbnm[i] = fmaf(hmeanv[(size_t)(n * CC) * VV + i], s, off);
  }
  if (tid < CC) spool[tid] = pooled[n * CC + tid];
  __syncthreads();
  for (int i = tid; i < NCLS * VV; i += 256) {
    const int o = i / VV, v = i - o * VV;
    float a = 0.f;
    for (int c = 0; c < CC; ++c) a = fmaf(attw[o * CC + c], sbnm[c * VV + v], a);
    sxam[i] = a;
  }
  if (tid < NCLS) {
    float a = fcb[tid];
    for (int c = 0; c < CC; ++c) a = fmaf(spool[c], fcw[tid * CC + c], a);
    dout[n * NCLS + tid] = a;
  }
  __syncthreads();
  for (int i = tid; i < NAE * VV * VV; i += 256) {
    const int j = i / VV, v = i - j * VV;
    float a = 0.f;
    for (int o = 0; o < NCLS; ++o) a = fmaf(edgew[j * NCLS + o], sxam[o * VV + v], a);
    const float s = eg[j] * rsqrtf(ev[j] + EPS);
    const float val = tanhf(fmaf(a - em[j], s, eb[j]));
    dout[NN * NCLS + (size_t)NN * TV + (size_t)n * NAE * VV * VV + i] = fmaxf(val, 0.f);
  }
}

// ---------------------------------------------------------------------------
// K3c: node attention  (unchanged)
// ---------------------------------------------------------------------------
__global__ __launch_bounds__(256) void k_node(
    const float* __restrict__ h,
    const float* __restrict__ ag, const float* __restrict__ ab,
    const float* __restrict__ am, const float* __restrict__ av,
    const float* __restrict__ attw, const float* __restrict__ nodew,
    const float* __restrict__ ng, const float* __restrict__ nb,
    const float* __restrict__ nm, const float* __restrict__ nv,
    float* __restrict__ dout)
{
  const int tid = threadIdx.x;
  __shared__ float ac[CC];
  __shared__ float tmp[CC];
  if (tid < CC) {
    float nc = 0.f;
    for (int o = 0; o < NCLS; ++o) nc = fmaf(nodew[o], attw[o * CC + tid], nc);
    const float s = ag[tid] * rsqrtf(av[tid] + EPS);
    const float off = ab[tid] - am[tid] * s;
    ac[tid] = nc * s;
    tmp[tid] = nc * off;
  }
  __syncthreads();
  if (tid == 0) {
    float b = 0.f;
    for (int c = 0; c < CC; ++c) b += tmp[c];
    tmp[0] = b;
  }
  __syncthreads();
  const float b0 = tmp[0];
  const size_t i = (size_t)blockIdx.x * 256 + tid;
  if (i < (size_t)NN * TV) {
    const int n = (int)(i / TV), f = (int)(i - (size_t)n * TV);
    const float* hb = h + (size_t)n * CC * TV + f;
    float xsum = b0;
    #pragma unroll 8
    for (int c = 0; c < CC; ++c) xsum = fmaf(hb[(size_t)c * TV], ac[c], xsum);
    const float s = ng[0] * rsqrtf(nv[0] + EPS);
    const float y = fmaf(xsum - nm[0], s, nb[0]);
    dout[NN * NCLS + i] = 1.f / (1.f + expf(-y));
  }
}

// ---------------------------------------------------------------------------
extern "C" void kernel_launch(void* const* d_in, const int* in_sizes, int n_in,
                              void* d_out, int out_size, void* d_ws, size_t ws_size,
                              hipStream_t stream) {
  const float* x        = (const float*)d_in[0];
  const float* A        = (const float*)d_in[1];
  const float* sgc_w    = (const float*)d_in[2];
  const float* sgc_b    = (const float*)d_in[3];
  const float* M        = (const float*)d_in[4];
  const float* bnA_g    = (const float*)d_in[5];
  const float* bnA_b    = (const float*)d_in[6];
  const float* bnA_m    = (const float*)d_in[7];
  const float* bnA_v    = (const float*)d_in[8];
  const float* tconv_w  = (const float*)d_in[9];
  const float* tconv_b  = (const float*)d_in[10];
  const float* bnB_g    = (const float*)d_in[11];
  const float* bnB_b    = (const float*)d_in[12];
  const float* bnB_m    = (const float*)d_in[13];
  const float* bnB_v    = (const float*)d_in[14];
  const float* fc_w     = (const float*)d_in[15];
  const float* fc_b     = (const float*)d_in[16];
  const float* attbn_g  = (const float*)d_in[17];
  const float* attbn_b  = (const float*)d_in[18];
  const float* attbn_m  = (const float*)d_in[19];
  const float* attbn_v  = (const float*)d_in[20];
  // d_in[21..34]: transformer branch params — dead code in the reference.
  const float* attconv_w  = (const float*)d_in[35];
  const float* nodeconv_w = (const float*)d_in[36];
  const float* nodebn_g   = (const float*)d_in[37];
  const float* nodebn_b   = (const float*)d_in[38];
  const float* nodebn_m   = (const float*)d_in[39];
  const float* nodebn_v   = (const float*)d_in[40];
  const float* edgeconv_w = (const float*)d_in[41];
  const float* edgebn_g   = (const float*)d_in[42];
  const float* edgebn_b   = (const float*)d_in[43];
  const float* edgebn_m   = (const float*)d_in[44];
  const float* edgebn_v   = (const float*)d_in[45];

  // workspace layout
  float* pooled = (float*)d_ws;                        // 1024
  float* hmeanv = pooled + NN * CC;                    // 16*64*26
  float* bufA   = hmeanv + (size_t)NN * CC * VV;       // 16*64*TV f32
  float* bufB   = bufA + (size_t)NN * CC * TV;         // 16*64*TV f32
  unsigned short* y1 = (unsigned short*)(bufB + (size_t)NN * CC * TV);
  float* out = (float*)d_out;

  // n-grouping for y1 (bf16): pick largest group fitting ws_size
  const size_t base_bytes = ((size_t)NN * CC + (size_t)NN * CC * VV
                             + 2 * (size_t)NN * CC * TV) * 4;
  int G = NN;
  while (G > 1 && base_bytes + (size_t)G * OO * TV * 2 > ws_size) G >>= 1;

  const int NFT = (TV + 127) >> 7;   // 129
  const int NTT = (TT_ + 3) >> 2;    // 159
  const int NF  = (TV + 63) / 64;    // 258
  for (int i = 0; i < 3; ++i) {
    const float* src = (i == 0) ? x : bufB;
    for (int g = 0; g < NN; g += G) {
      k_sgc_pw<<<G * KK * NFT, 256, 0, stream>>>(
          src + (size_t)g * CC * TV, sgc_w + (size_t)i * OO * CC,
          sgc_b + i * OO, y1, G);
      k_sgc_graph2<<<G * NTT, 256, 0, stream>>>(
          y1, A, M + (size_t)i * KK * VV * VV,
          bnA_g + i * CC, bnA_b + i * CC, bnA_m + i * CC, bnA_v + i * CC,
          bufA + (size_t)g * CC * TV, G);
    }
    k_tconv<<<NN * NF, 256, 0, stream>>>(
        bufA, tconv_w + (size_t)i * CC * CC * TKK, tconv_b + i * CC,
        bnB_g + i * CC, bnB_b + i * CC, bnB_m + i * CC, bnB_v + i * CC, bufB);
  }
  k_pool<<<NN * CC, 256, 0, stream>>>(bufB, pooled, hmeanv);
  k_head_edge<<<NN, 256, 0, stream>>>(pooled, hmeanv, fc_w, fc_b,
      attbn_g, attbn_b, attbn_m, attbn_v, attconv_w, edgeconv_w,
      edgebn_g, edgebn_b, edgebn_m, edgebn_v, out);
  k_node<<<((size_t)NN * TV + 255) / 256, 256, 0, stream>>>(
      bufB, attbn_g, attbn_b, attbn_m, attbn_v, attconv_w, nodeconv_w,
      nodebn_g, nodebn_b, nodebn_m, nodebn_v, out);
}

// Round 4
// 1286.320 us; speedup vs baseline: 2.1292x; 1.5903x over previous
//
#include <hip/hip_runtime.h>
#include <hip/hip_bf16.h>
#include <math.h>

#define NN 16
#define CC 64
#define TT_ 634
#define VV 26
#define TV 16484      // TT_*VV
#define KK 3
#define OO 192        // KK*CC
#define TKK 9
#define NCLS 60
#define NAE 4
#define EPS 1e-5f

typedef __attribute__((ext_vector_type(8))) short short8;
typedef __attribute__((ext_vector_type(4))) float f32x4;

static __device__ __forceinline__ float bf2f(unsigned int u) {
  union { unsigned int i; float f; } v; v.i = u << 16; return v.f;
}
static __device__ __forceinline__ unsigned int f2bf(float x) {
  union { float f; unsigned int i; } v; v.f = x;
  unsigned int r = v.i + 0x7fffu + ((v.i >> 16) & 1u);
  return r >> 16;
}

// ---------------------------------------------------------------------------
// S1: y1[n][o][f] (bf16) = sum_c W[o][c] * h[n][c][f] + Wb[o]   (unchanged)
// ---------------------------------------------------------------------------
__global__ __launch_bounds__(256) void k_sgc_pw(
    const float* __restrict__ hin,          // [ncount][64][TV]
    const float* __restrict__ W,            // [192][64]
    const float* __restrict__ Wb,           // [192]
    unsigned short* __restrict__ y1,        // [ncount][192][TV] bf16
    int ncount)
{
  const int NFT = (TV + 127) >> 7;  // 129
  const int tid = threadIdx.x;
  int bid = blockIdx.x;
  const int ft = bid % NFT; bid /= NFT;
  const int ot = bid % KK;  bid /= KK;
  const int n  = bid;
  const int f0 = ft << 7;
  const int o0 = ot << 6;
  __shared__ float sW[CC][68];
  __shared__ float sH[CC][128];
  for (int l = tid; l < CC * CC; l += 256) {
    const int o = l >> 6, c = l & 63;
    sW[c][o] = W[(size_t)(o0 + o) * CC + c];
  }
  const float* hb = hin + (size_t)n * CC * TV;
  for (int l = tid; l < CC * 128; l += 256) {
    const int c = l >> 7, f = l & 127;
    const int fg = f0 + f;
    sH[c][f] = (fg < TV) ? hb[(size_t)c * TV + fg] : 0.f;
  }
  __syncthreads();
  const int ogrp = tid >> 5;
  const int fgrp = tid & 31;
  const int ol = ogrp << 3, fl = fgrp << 2;
  float acc[8][4] = {};
  #pragma unroll 4
  for (int k = 0; k < CC; ++k) {
    const float4 w0 = *(const float4*)&sW[k][ol];
    const float4 w1 = *(const float4*)&sW[k][ol + 4];
    const float4 hv = *(const float4*)&sH[k][fl];
    const float wv[8] = {w0.x, w0.y, w0.z, w0.w, w1.x, w1.y, w1.z, w1.w};
    const float hf[4] = {hv.x, hv.y, hv.z, hv.w};
    #pragma unroll
    for (int a = 0; a < 8; ++a)
      #pragma unroll
      for (int b = 0; b < 4; ++b)
        acc[a][b] = fmaf(wv[a], hf[b], acc[a][b]);
  }
  const int fg = f0 + fl;
  if (fg < TV) {
    #pragma unroll
    for (int a = 0; a < 8; ++a) {
      const int o = o0 + ol + a;
      const float bias = Wb[o];
      uint2 pk;
      pk.x = f2bf(acc[a][0] + bias) | (f2bf(acc[a][1] + bias) << 16);
      pk.y = f2bf(acc[a][2] + bias) | (f2bf(acc[a][3] + bias) << 16);
      *(uint2*)(y1 + ((size_t)n * OO + o) * TV + fg) = pk;
    }
  }
}

// ---------------------------------------------------------------------------
// S2: graph contraction; writes bf16 output (feeds MFMA tconv)
// ---------------------------------------------------------------------------
__global__ __launch_bounds__(256) void k_sgc_graph2(
    const unsigned short* __restrict__ y1,  // [ncount][192][TV] bf16
    const float* __restrict__ Ap, const float* __restrict__ Mp,
    const float* __restrict__ bg, const float* __restrict__ bb,
    const float* __restrict__ bm, const float* __restrict__ bv,
    unsigned short* __restrict__ hout,      // [ncount][64][TV] bf16
    int ncount)
{
  const int NTT = (TT_ + 3) >> 2;  // 159
  const int tid = threadIdx.x;
  const int tt = blockIdx.x % NTT;
  const int n  = blockIdx.x / NTT;
  const int t0 = tt << 2;
  const int f0 = t0 * VV;
  __shared__ unsigned short sy[KK][4][VV][72];
  __shared__ float sAM[KK][VV][28];
  for (int l = tid; l < KK * VV * 28; l += 256) {
    const int k = l / (VV * 28), r = l % (VV * 28);
    const int v = r / 28, w = r % 28;
    sAM[k][v][w] = (w < VV) ? Ap[(k * VV + v) * VV + w] * Mp[(k * VV + v) * VV + w]
                            : 0.f;
  }
  const unsigned short* yb = y1 + (size_t)n * OO * TV;
  for (int l = tid; l < OO * 52; l += 256) {
    const int o = l / 52, j = l % 52;
    const int f = f0 + 2 * j;
    unsigned int val = 0;
    if (f + 2 <= TV) val = *(const unsigned int*)(yb + (size_t)o * TV + f);
    const int k = o >> 6, c = o & 63;
    const int floc = 2 * j;
    const int tl = floc / VV, v = floc % VV;
    sy[k][tl][v][c]     = (unsigned short)(val & 0xffffu);
    sy[k][tl][v + 1][c] = (unsigned short)(val >> 16);
  }
  __syncthreads();
  const int tl = tid >> 6;
  const int cg = (tid >> 3) & 7;
  const int wq = tid & 7;
  const int c0 = cg << 3, w0 = wq << 2;
  float acc[8][4] = {};
  if (wq < 7) {
    for (int k = 0; k < KK; ++k) {
      #pragma unroll 2
      for (int v = 0; v < VV; ++v) {
        const float4 am = *(const float4*)&sAM[k][v][w0];
        const uint4 yv = *(const uint4*)&sy[k][tl][v][c0];
        float yf[8];
        yf[0] = bf2f(yv.x & 0xffffu); yf[1] = bf2f(yv.x >> 16);
        yf[2] = bf2f(yv.y & 0xffffu); yf[3] = bf2f(yv.y >> 16);
        yf[4] = bf2f(yv.z & 0xffffu); yf[5] = bf2f(yv.z >> 16);
        yf[6] = bf2f(yv.w & 0xffffu); yf[7] = bf2f(yv.w >> 16);
        const float amf[4] = {am.x, am.y, am.z, am.w};
        #pragma unroll
        for (int a = 0; a < 8; ++a)
          #pragma unroll
          for (int b = 0; b < 4; ++b)
            acc[a][b] = fmaf(yf[a], amf[b], acc[a][b]);
      }
    }
  }
  const int t = t0 + tl;
  if (wq < 7 && t < TT_) {
    #pragma unroll
    for (int a = 0; a < 8; ++a) {
      const int c = c0 + a;
      const float s = bg[c] * rsqrtf(bv[c] + EPS);
      const float off = bb[c] - bm[c] * s;
      unsigned short* ob = hout + ((size_t)n * CC + c) * TV + t * VV + w0;
      const float r0 = fmaxf(fmaf(acc[a][0], s, off), 0.f);
      const float r1 = fmaxf(fmaf(acc[a][1], s, off), 0.f);
      const float r2 = fmaxf(fmaf(acc[a][2], s, off), 0.f);
      const float r3 = fmaxf(fmaf(acc[a][3], s, off), 0.f);
      if (w0 + 4 <= VV) {
        *(unsigned int*)ob       = f2bf(r0) | (f2bf(r1) << 16);
        *(unsigned int*)(ob + 2) = f2bf(r2) | (f2bf(r3) << 16);
      } else {
        const float vals[4] = {r0, r1, r2, r3};
        #pragma unroll
        for (int b = 0; b < 4; ++b)
          if (w0 + b < VV) ob[b] = (unsigned short)f2bf(vals[b]);
      }
    }
  }
}

// ---------------------------------------------------------------------------
// W2 prep: tconv weights [c][ci][dt] f32 -> [c][dt*64+ci] bf16 (k-contiguous)
// ---------------------------------------------------------------------------
__global__ __launch_bounds__(256) void k_prep_w2(
    const float* __restrict__ wt, unsigned short* __restrict__ W2)
{
  const int i = blockIdx.x * 256 + threadIdx.x;
  if (i < CC * 576) {
    const int c = i / 576, k = i % 576;
    const int dt = k >> 6, ci = k & 63;
    W2[i] = (unsigned short)f2bf(wt[c * 576 + ci * 9 + dt]);
  }
}

// ---------------------------------------------------------------------------
// K2 (MFMA): out[c][f] = sum_{dt,ci} W[c][dt,ci] * in[ci][f+(dt-4)*26]
// GEMM M=64, N=256/block, K=576 via mfma_f32_16x16x32_bf16.
// LDS: input window transposed [f_local 464][ci 64] bf16, XOR-swizzled
// (granule g = (ci>>3) ^ (f_local&7)) to kill the stride-128B bank conflict.
// A-frags prefetched from global W2 (L2-resident, 74 KB) one k-step ahead.
// 4 waves x (64m x 64n); per k-step/wave: 4 A + 4 B(b128) + 16 MFMA.
// ---------------------------------------------------------------------------
__global__ __launch_bounds__(256) void k_tconv_mfma(
    const unsigned short* __restrict__ xin,  // [16][64][TV] bf16
    const unsigned short* __restrict__ W2,   // [64][576] bf16
    const float* __restrict__ wb, const float* __restrict__ bg,
    const float* __restrict__ bb, const float* __restrict__ bm,
    const float* __restrict__ bv, float* __restrict__ xout)
{
  const int NFT = (TV + 255) >> 8;  // 65
  const int n = blockIdx.x / NFT, ft = blockIdx.x % NFT;
  const int f0 = ft << 8;
  const int tid = threadIdx.x;
  const int w = tid >> 6, lane = tid & 63;
  const int l15 = lane & 15, l4 = lane >> 4;
  __shared__ unsigned short sIn[464 * 64];  // 59392 B

  // ---- stage input window, transposed + swizzled ----
  const unsigned short* xb = xin + (size_t)n * CC * TV;
  for (int it = tid; it < 58 * 64; it += 256) {
    const int ci = it & 63, fc = it >> 6;   // fc 0..57
    const int flb = fc << 3;
    const int fg = f0 - 104 + flb;
    unsigned short e[8];
    if (fg >= 0 && fg + 8 <= TV) {
      const uint2 v0 = *(const uint2*)(xb + (size_t)ci * TV + fg);
      const uint2 v1 = *(const uint2*)(xb + (size_t)ci * TV + fg + 4);
      e[0] = (unsigned short)(v0.x & 0xffffu); e[1] = (unsigned short)(v0.x >> 16);
      e[2] = (unsigned short)(v0.y & 0xffffu); e[3] = (unsigned short)(v0.y >> 16);
      e[4] = (unsigned short)(v1.x & 0xffffu); e[5] = (unsigned short)(v1.x >> 16);
      e[6] = (unsigned short)(v1.y & 0xffffu); e[7] = (unsigned short)(v1.y >> 16);
    } else {
      #pragma unroll
      for (int j = 0; j < 8; ++j) {
        const int f = fg + j;
        e[j] = (f >= 0 && f < TV) ? xb[(size_t)ci * TV + f] : (unsigned short)0;
      }
    }
    const int cg8 = ci >> 3, cl = ci & 7;
    #pragma unroll
    for (int j = 0; j < 8; ++j) {     // flb%8==0 -> (fl&7)==j
      sIn[((flb + j) << 6) + ((cg8 ^ j) << 3) + cl] = e[j];
    }
  }
  __syncthreads();

  // ---- K loop: 18 steps of 32 (dt = s>>1, ci0 = (s&1)*32) ----
  const int w64 = w << 6;
  f32x4 acc[4][4] = {};     // [m-tile][n-tile]
  short8 aCur[4], aNxt[4];
  {
    const int koff = (l4 << 3);   // s=0: dt=0, ci0=0
    #pragma unroll
    for (int mt = 0; mt < 4; ++mt)
      aCur[mt] = *(const short8*)(W2 + (size_t)(mt * 16 + l15) * 576 + koff);
  }
  for (int s = 0; s < 18; ++s) {
    if (s < 17) {
      const int s1 = s + 1;
      const int koff = ((s1 >> 1) << 6) + ((s1 & 1) << 5) + (l4 << 3);
      #pragma unroll
      for (int mt = 0; mt < 4; ++mt)
        aNxt[mt] = *(const short8*)(W2 + (size_t)(mt * 16 + l15) * 576 + koff);
    }
    const int dt = s >> 1;
    const int cg = ((s & 1) << 2) + l4;           // ci granule 0..7
    const int flb = w64 + l15 + (dt - 4) * 26 + 104;
    short8 bfrag[4];
    #pragma unroll
    for (int nt = 0; nt < 4; ++nt) {
      const int fl = flb + (nt << 4);
      bfrag[nt] = *(const short8*)&sIn[(fl << 6) + ((cg ^ (fl & 7)) << 3)];
    }
    #pragma unroll
    for (int mt = 0; mt < 4; ++mt)
      #pragma unroll
      for (int nt = 0; nt < 4; ++nt)
        acc[mt][nt] = __builtin_amdgcn_mfma_f32_16x16x32_bf16(
            aCur[mt], bfrag[nt], acc[mt][nt], 0, 0, 0);
    if (s < 17) {
      #pragma unroll
      for (int mt = 0; mt < 4; ++mt) aCur[mt] = aNxt[mt];
    }
  }

  // ---- epilogue: bias + BN + ReLU, f32 store ----
  float* ob = xout + (size_t)n * CC * TV;
  #pragma unroll
  for (int mt = 0; mt < 4; ++mt) {
    #pragma unroll
    for (int r = 0; r < 4; ++r) {
      const int c = mt * 16 + (l4 << 2) + r;
      const float sc = bg[c] * rsqrtf(bv[c] + EPS);
      const float off = fmaf(wb[c] - bm[c], sc, bb[c]);
      #pragma unroll
      for (int nt = 0; nt < 4; ++nt) {
        const int f = f0 + w64 + (nt << 4) + l15;
        if (f < TV)
          ob[(size_t)c * TV + f] = fmaxf(fmaf(acc[mt][nt][r], sc, off), 0.f);
      }
    }
  }
}

// ---------------------------------------------------------------------------
// K3a: pooled / per-v T-mean  (unchanged, reads f32 bufB)
// ---------------------------------------------------------------------------
__global__ __launch_bounds__(256) void k_pool(
    const float* __restrict__ h, float* __restrict__ pooled,
    float* __restrict__ hmeanv)
{
  const int tid = threadIdx.x;
  const int bid = blockIdx.x;
  const float* row = h + (size_t)bid * TV;
  __shared__ float part[9 * VV];
  if (tid < 9 * VV) {
    const int tt = tid / VV, v = tid - tt * VV;
    float s = 0.f;
    for (int t = tt; t < TT_; t += 9) s += row[t * VV + v];
    part[tid] = s;
  }
  __syncthreads();
  if (tid < VV) {
    float tot = 0.f;
    #pragma unroll
    for (int j = 0; j < 9; ++j) tot += part[j * VV + tid];
    hmeanv[(size_t)bid * VV + tid] = tot / (float)TT_;
    part[tid] = tot;
  }
  __syncthreads();
  if (tid == 0) {
    float tot = 0.f;
    for (int v = 0; v < VV; ++v) tot += part[v];
    pooled[bid] = tot / (float)TV;
  }
}

// ---------------------------------------------------------------------------
// K3b: per-n head  (unchanged)
// ---------------------------------------------------------------------------
__global__ __launch_bounds__(256) void k_head_edge(
    const float* __restrict__ pooled, const float* __restrict__ hmeanv,
    const float* __restrict__ fcw, const float* __restrict__ fcb,
    const float* __restrict__ ag, const float* __restrict__ ab,
    const float* __restrict__ am, const float* __restrict__ av,
    const float* __restrict__ attw, const float* __restrict__ edgew,
    const float* __restrict__ eg, const float* __restrict__ eb,
    const float* __restrict__ em, const float* __restrict__ ev,
    float* __restrict__ dout)
{
  const int tid = threadIdx.x;
  const int n = blockIdx.x;
  __shared__ float sbnm[CC * VV];
  __shared__ float sxam[NCLS * VV];
  __shared__ float spool[CC];
  for (int i = tid; i < CC * VV; i += 256) {
    const int c = i / VV;
    const float s = ag[c] * rsqrtf(av[c] + EPS);
    const float off = ab[c] - am[c] * s;
    sbnm[i] = fmaf(hmeanv[(size_t)(n * CC) * VV + i], s, off);
  }
  if (tid < CC) spool[tid] = pooled[n * CC + tid];
  __syncthreads();
  for (int i = tid; i < NCLS * VV; i += 256) {
    const int o = i / VV, v = i - o * VV;
    float a = 0.f;
    for (int c = 0; c < CC; ++c) a = fmaf(attw[o * CC + c], sbnm[c * VV + v], a);
    sxam[i] = a;
  }
  if (tid < NCLS) {
    float a = fcb[tid];
    for (int c = 0; c < CC; ++c) a = fmaf(spool[c], fcw[tid * CC + c], a);
    dout[n * NCLS + tid] = a;
  }
  __syncthreads();
  for (int i = tid; i < NAE * VV * VV; i += 256) {
    const int j = i / VV, v = i - j * VV;
    float a = 0.f;
    for (int o = 0; o < NCLS; ++o) a = fmaf(edgew[j * NCLS + o], sxam[o * VV + v], a);
    const float s = eg[j] * rsqrtf(ev[j] + EPS);
    const float val = tanhf(fmaf(a - em[j], s, eb[j]));
    dout[NN * NCLS + (size_t)NN * TV + (size_t)n * NAE * VV * VV + i] = fmaxf(val, 0.f);
  }
}

// ---------------------------------------------------------------------------
// K3c: node attention  (unchanged)
// ---------------------------------------------------------------------------
__global__ __launch_bounds__(256) void k_node(
    const float* __restrict__ h,
    const float* __restrict__ ag, const float* __restrict__ ab,
    const float* __restrict__ am, const float* __restrict__ av,
    const float* __restrict__ attw, const float* __restrict__ nodew,
    const float* __restrict__ ng, const float* __restrict__ nb,
    const float* __restrict__ nm, const float* __restrict__ nv,
    float* __restrict__ dout)
{
  const int tid = threadIdx.x;
  __shared__ float ac[CC];
  __shared__ float tmp[CC];
  if (tid < CC) {
    float nc = 0.f;
    for (int o = 0; o < NCLS; ++o) nc = fmaf(nodew[o], attw[o * CC + tid], nc);
    const float s = ag[tid] * rsqrtf(av[tid] + EPS);
    const float off = ab[tid] - am[tid] * s;
    ac[tid] = nc * s;
    tmp[tid] = nc * off;
  }
  __syncthreads();
  if (tid == 0) {
    float b = 0.f;
    for (int c = 0; c < CC; ++c) b += tmp[c];
    tmp[0] = b;
  }
  __syncthreads();
  const float b0 = tmp[0];
  const size_t i = (size_t)blockIdx.x * 256 + tid;
  if (i < (size_t)NN * TV) {
    const int n = (int)(i / TV), f = (int)(i - (size_t)n * TV);
    const float* hb = h + (size_t)n * CC * TV + f;
    float xsum = b0;
    #pragma unroll 8
    for (int c = 0; c < CC; ++c) xsum = fmaf(hb[(size_t)c * TV], ac[c], xsum);
    const float s = ng[0] * rsqrtf(nv[0] + EPS);
    const float y = fmaf(xsum - nm[0], s, nb[0]);
    dout[NN * NCLS + i] = 1.f / (1.f + expf(-y));
  }
}

// ---------------------------------------------------------------------------
extern "C" void kernel_launch(void* const* d_in, const int* in_sizes, int n_in,
                              void* d_out, int out_size, void* d_ws, size_t ws_size,
                              hipStream_t stream) {
  const float* x        = (const float*)d_in[0];
  const float* A        = (const float*)d_in[1];
  const float* sgc_w    = (const float*)d_in[2];
  const float* sgc_b    = (const float*)d_in[3];
  const float* M        = (const float*)d_in[4];
  const float* bnA_g    = (const float*)d_in[5];
  const float* bnA_b    = (const float*)d_in[6];
  const float* bnA_m    = (const float*)d_in[7];
  const float* bnA_v    = (const float*)d_in[8];
  const float* tconv_w  = (const float*)d_in[9];
  const float* tconv_b  = (const float*)d_in[10];
  const float* bnB_g    = (const float*)d_in[11];
  const float* bnB_b    = (const float*)d_in[12];
  const float* bnB_m    = (const float*)d_in[13];
  const float* bnB_v    = (const float*)d_in[14];
  const float* fc_w     = (const float*)d_in[15];
  const float* fc_b     = (const float*)d_in[16];
  const float* attbn_g  = (const float*)d_in[17];
  const float* attbn_b  = (const float*)d_in[18];
  const float* attbn_m  = (const float*)d_in[19];
  const float* attbn_v  = (const float*)d_in[20];
  // d_in[21..34]: transformer branch params — dead code in the reference.
  const float* attconv_w  = (const float*)d_in[35];
  const float* nodeconv_w = (const float*)d_in[36];
  const float* nodebn_g   = (const float*)d_in[37];
  const float* nodebn_b   = (const float*)d_in[38];
  const float* nodebn_m   = (const float*)d_in[39];
  const float* nodebn_v   = (const float*)d_in[40];
  const float* edgeconv_w = (const float*)d_in[41];
  const float* edgebn_g   = (const float*)d_in[42];
  const float* edgebn_b   = (const float*)d_in[43];
  const float* edgebn_m   = (const float*)d_in[44];
  const float* edgebn_v   = (const float*)d_in[45];

  // workspace layout
  float* pooled = (float*)d_ws;                              // 1024 f32
  float* hmeanv = pooled + NN * CC;                          // 26624 f32
  unsigned short* W2 = (unsigned short*)(hmeanv + (size_t)NN * CC * VV);
  unsigned short* bufA = W2 + (size_t)CC * 576;              // bf16 act
  float* bufB = (float*)(bufA + (size_t)NN * CC * TV);       // f32 act
  unsigned short* y1 = (unsigned short*)(bufB + (size_t)NN * CC * TV);
  float* out = (float*)d_out;

  const size_t base_bytes = ((size_t)NN * CC + (size_t)NN * CC * VV
                             + (size_t)NN * CC * TV) * 4
                            + ((size_t)CC * 576 + (size_t)NN * CC * TV) * 2;
  int G = NN;
  while (G > 1 && base_bytes + (size_t)G * OO * TV * 2 > ws_size) G >>= 1;

  const int NFT = (TV + 127) >> 7;   // 129
  const int NTT = (TT_ + 3) >> 2;    // 159
  const int NFC = (TV + 255) >> 8;   // 65
  for (int i = 0; i < 3; ++i) {
    const float* src = (i == 0) ? x : bufB;
    k_prep_w2<<<(CC * 576 + 255) / 256, 256, 0, stream>>>(
        tconv_w + (size_t)i * CC * CC * TKK, W2);
    for (int g = 0; g < NN; g += G) {
      k_sgc_pw<<<G * KK * NFT, 256, 0, stream>>>(
          src + (size_t)g * CC * TV, sgc_w + (size_t)i * OO * CC,
          sgc_b + i * OO, y1, G);
      k_sgc_graph2<<<G * NTT, 256, 0, stream>>>(
          y1, A, M + (size_t)i * KK * VV * VV,
          bnA_g + i * CC, bnA_b + i * CC, bnA_m + i * CC, bnA_v + i * CC,
          bufA + (size_t)g * CC * TV, G);
    }
    k_tconv_mfma<<<NN * NFC, 256, 0, stream>>>(
        bufA, W2, tconv_b + i * CC,
        bnB_g + i * CC, bnB_b + i * CC, bnB_m + i * CC, bnB_v + i * CC, bufB);
  }
  k_pool<<<NN * CC, 256, 0, stream>>>(bufB, pooled, hmeanv);
  k_head_edge<<<NN, 256, 0, stream>>>(pooled, hmeanv, fc_w, fc_b,
      attbn_g, attbn_b, attbn_m, attbn_v, attconv_w, edgeconv_w,
      edgebn_g, edgebn_b, edgebn_m, edgebn_v, out);
  k_node<<<((size_t)NN * TV + 255) / 256, 256, 0, stream>>>(
      bufB, attbn_g, attbn_b, attbn_m, attbn_v, attconv_w, nodeconv_w,
      nodebn_g, nodebn_b, nodebn_m, nodebn_v, out);
}

// Round 5
// 1091.024 us; speedup vs baseline: 2.5103x; 1.1790x over previous
//
#include <hip/hip_runtime.h>
#include <hip/hip_bf16.h>
#include <math.h>

#define NN 16
#define CC 64
#define TT_ 634
#define VV 26
#define TV 16484      // TT_*VV
#define KK 3
#define OO 192        // KK*CC
#define TKK 9
#define NCLS 60
#define NAE 4
#define EPS 1e-5f

typedef __attribute__((ext_vector_type(8))) short short8;
typedef __attribute__((ext_vector_type(4))) float f32x4;

static __device__ __forceinline__ float bf2f(unsigned int u) {
  union { unsigned int i; float f; } v; v.i = u << 16; return v.f;
}
static __device__ __forceinline__ unsigned int f2bf(float x) {
  union { float f; unsigned int i; } v; v.f = x;
  unsigned int r = v.i + 0x7fffu + ((v.i >> 16) & 1u);
  return r >> 16;
}

// ---------------------------------------------------------------------------
// W1 prep: sgc weights [192][64] f32 -> bf16 (layout already k-contiguous)
// ---------------------------------------------------------------------------
__global__ __launch_bounds__(256) void k_prep_w1(
    const float* __restrict__ w, unsigned short* __restrict__ W1)
{
  const int i = blockIdx.x * 256 + threadIdx.x;
  if (i < OO * CC) W1[i] = (unsigned short)f2bf(w[i]);
}

// ---------------------------------------------------------------------------
// S1 (MFMA): y1[n][o][f] (bf16) = sum_ci W[o][ci] * h[n][ci][f] + Wb[o]
// GEMM M=192, K=64, N=128/block via mfma_f32_16x16x32_bf16.
// 4 waves as 2m x 2n: wave tile 96(m) x 64(n). LDS: h tile transposed
// [f 128][ci 64] bf16, XOR-swizzled (granule g = (ci>>3) ^ (f&7)) — same
// staging/fragment template as k_tconv_mfma (validated in R4).
// f32 h converted to bf16 during staging (keeps dataflow unchanged).
// ---------------------------------------------------------------------------
__global__ __launch_bounds__(256) void k_sgc_pw_mfma(
    const float* __restrict__ hin,          // [16][64][TV] f32
    const unsigned short* __restrict__ W1,  // [192][64] bf16
    const float* __restrict__ Wb,           // [192]
    unsigned short* __restrict__ y1)        // [16][192][TV] bf16
{
  const int NFT = (TV + 127) >> 7;  // 129
  const int n = blockIdx.x / NFT, ft = blockIdx.x % NFT;
  const int f0 = ft << 7;
  const int tid = threadIdx.x;
  const int w = tid >> 6, lane = tid & 63;
  const int l15 = lane & 15, l4 = lane >> 4;
  const int m0 = (w >> 1) * 96;    // 0 or 96
  const int n0 = (w & 1) * 64;     // 0 or 64
  __shared__ unsigned short sIn[128 * 64];  // 16 KB, [f][ci] swizzled

  // ---- stage h tile: f32 -> bf16, transposed + swizzled ----
  const float* hb = hin + (size_t)n * CC * TV;
  for (int it = tid; it < 16 * 64; it += 256) {
    const int ci = it & 63, fc = it >> 6;   // fc 0..15
    const int flb = fc << 3;
    const int fg = f0 + flb;
    float e[8];
    if (fg + 8 <= TV) {
      const float4 v0 = *(const float4*)(hb + (size_t)ci * TV + fg);
      const float4 v1 = *(const float4*)(hb + (size_t)ci * TV + fg + 4);
      e[0] = v0.x; e[1] = v0.y; e[2] = v0.z; e[3] = v0.w;
      e[4] = v1.x; e[5] = v1.y; e[6] = v1.z; e[7] = v1.w;
    } else {
      #pragma unroll
      for (int j = 0; j < 8; ++j) {
        const int f = fg + j;
        e[j] = (f < TV) ? hb[(size_t)ci * TV + f] : 0.f;
      }
    }
    const int cg8 = ci >> 3, cl = ci & 7;
    #pragma unroll
    for (int j = 0; j < 8; ++j) {   // flb%8==0 -> ((flb+j)&7)==j
      sIn[((flb + j) << 6) + (((cg8 ^ j)) << 3) + cl] = (unsigned short)f2bf(e[j]);
    }
  }
  __syncthreads();

  // ---- A-fragments from global W1 (L2-resident, 24 KB) ----
  short8 afr[2][6];
  #pragma unroll
  for (int ks = 0; ks < 2; ++ks)
    #pragma unroll
    for (int mf = 0; mf < 6; ++mf) {
      const int o = m0 + mf * 16 + l15;
      afr[ks][mf] = *(const short8*)(W1 + (size_t)o * CC + (ks << 5) + (l4 << 3));
    }

  // ---- MFMA: 2 k-steps x 6 m x 4 n ----
  f32x4 acc[6][4] = {};
  #pragma unroll
  for (int ks = 0; ks < 2; ++ks) {
    short8 bfr[4];
    const int cg = (ks << 2) + l4;   // ci granule 0..7
    #pragma unroll
    for (int nf = 0; nf < 4; ++nf) {
      const int fl = n0 + (nf << 4) + l15;
      bfr[nf] = *(const short8*)&sIn[(fl << 6) + ((cg ^ (fl & 7)) << 3)];
    }
    #pragma unroll
    for (int mf = 0; mf < 6; ++mf)
      #pragma unroll
      for (int nf = 0; nf < 4; ++nf)
        acc[mf][nf] = __builtin_amdgcn_mfma_f32_16x16x32_bf16(
            afr[ks][mf], bfr[nf], acc[mf][nf], 0, 0, 0);
  }

  // ---- epilogue: +bias, bf16 store ----
  unsigned short* yb = y1 + (size_t)n * OO * TV;
  #pragma unroll
  for (int mf = 0; mf < 6; ++mf) {
    #pragma unroll
    for (int r = 0; r < 4; ++r) {
      const int o = m0 + mf * 16 + (l4 << 2) + r;
      const float bias = Wb[o];
      #pragma unroll
      for (int nf = 0; nf < 4; ++nf) {
        const int f = f0 + n0 + (nf << 4) + l15;
        if (f < TV)
          yb[(size_t)o * TV + f] = (unsigned short)f2bf(acc[mf][nf][r] + bias);
      }
    }
  }
}

// ---------------------------------------------------------------------------
// S2: graph contraction; writes bf16 output (feeds MFMA tconv)  (unchanged)
// ---------------------------------------------------------------------------
__global__ __launch_bounds__(256) void k_sgc_graph2(
    const unsigned short* __restrict__ y1,  // [ncount][192][TV] bf16
    const float* __restrict__ Ap, const float* __restrict__ Mp,
    const float* __restrict__ bg, const float* __restrict__ bb,
    const float* __restrict__ bm, const float* __restrict__ bv,
    unsigned short* __restrict__ hout,      // [ncount][64][TV] bf16
    int ncount)
{
  const int NTT = (TT_ + 3) >> 2;  // 159
  const int tid = threadIdx.x;
  const int tt = blockIdx.x % NTT;
  const int n  = blockIdx.x / NTT;
  const int t0 = tt << 2;
  const int f0 = t0 * VV;
  __shared__ unsigned short sy[KK][4][VV][72];
  __shared__ float sAM[KK][VV][28];
  for (int l = tid; l < KK * VV * 28; l += 256) {
    const int k = l / (VV * 28), r = l % (VV * 28);
    const int v = r / 28, w = r % 28;
    sAM[k][v][w] = (w < VV) ? Ap[(k * VV + v) * VV + w] * Mp[(k * VV + v) * VV + w]
                            : 0.f;
  }
  const unsigned short* yb = y1 + (size_t)n * OO * TV;
  for (int l = tid; l < OO * 52; l += 256) {
    const int o = l / 52, j = l % 52;
    const int f = f0 + 2 * j;
    unsigned int val = 0;
    if (f + 2 <= TV) val = *(const unsigned int*)(yb + (size_t)o * TV + f);
    const int k = o >> 6, c = o & 63;
    const int floc = 2 * j;
    const int tl = floc / VV, v = floc % VV;
    sy[k][tl][v][c]     = (unsigned short)(val & 0xffffu);
    sy[k][tl][v + 1][c] = (unsigned short)(val >> 16);
  }
  __syncthreads();
  const int tl = tid >> 6;
  const int cg = (tid >> 3) & 7;
  const int wq = tid & 7;
  const int c0 = cg << 3, w0 = wq << 2;
  float acc[8][4] = {};
  if (wq < 7) {
    for (int k = 0; k < KK; ++k) {
      #pragma unroll 2
      for (int v = 0; v < VV; ++v) {
        const float4 am = *(const float4*)&sAM[k][v][w0];
        const uint4 yv = *(const uint4*)&sy[k][tl][v][c0];
        float yf[8];
        yf[0] = bf2f(yv.x & 0xffffu); yf[1] = bf2f(yv.x >> 16);
        yf[2] = bf2f(yv.y & 0xffffu); yf[3] = bf2f(yv.y >> 16);
        yf[4] = bf2f(yv.z & 0xffffu); yf[5] = bf2f(yv.z >> 16);
        yf[6] = bf2f(yv.w & 0xffffu); yf[7] = bf2f(yv.w >> 16);
        const float amf[4] = {am.x, am.y, am.z, am.w};
        #pragma unroll
        for (int a = 0; a < 8; ++a)
          #pragma unroll
          for (int b = 0; b < 4; ++b)
            acc[a][b] = fmaf(yf[a], amf[b], acc[a][b]);
      }
    }
  }
  const int t = t0 + tl;
  if (wq < 7 && t < TT_) {
    #pragma unroll
    for (int a = 0; a < 8; ++a) {
      const int c = c0 + a;
      const float s = bg[c] * rsqrtf(bv[c] + EPS);
      const float off = bb[c] - bm[c] * s;
      unsigned short* ob = hout + ((size_t)n * CC + c) * TV + t * VV + w0;
      const float r0 = fmaxf(fmaf(acc[a][0], s, off), 0.f);
      const float r1 = fmaxf(fmaf(acc[a][1], s, off), 0.f);
      const float r2 = fmaxf(fmaf(acc[a][2], s, off), 0.f);
      const float r3 = fmaxf(fmaf(acc[a][3], s, off), 0.f);
      if (w0 + 4 <= VV) {
        *(unsigned int*)ob       = f2bf(r0) | (f2bf(r1) << 16);
        *(unsigned int*)(ob + 2) = f2bf(r2) | (f2bf(r3) << 16);
      } else {
        const float vals[4] = {r0, r1, r2, r3};
        #pragma unroll
        for (int b = 0; b < 4; ++b)
          if (w0 + b < VV) ob[b] = (unsigned short)f2bf(vals[b]);
      }
    }
  }
}

// ---------------------------------------------------------------------------
// W2 prep: tconv weights [c][ci][dt] f32 -> [c][dt*64+ci] bf16 (k-contiguous)
// ---------------------------------------------------------------------------
__global__ __launch_bounds__(256) void k_prep_w2(
    const float* __restrict__ wt, unsigned short* __restrict__ W2)
{
  const int i = blockIdx.x * 256 + threadIdx.x;
  if (i < CC * 576) {
    const int c = i / 576, k = i % 576;
    const int dt = k >> 6, ci = k & 63;
    W2[i] = (unsigned short)f2bf(wt[c * 576 + ci * 9 + dt]);
  }
}

// ---------------------------------------------------------------------------
// K2 (MFMA): temporal conv  (unchanged from R4 — validated)
// ---------------------------------------------------------------------------
__global__ __launch_bounds__(256) void k_tconv_mfma(
    const unsigned short* __restrict__ xin,  // [16][64][TV] bf16
    const unsigned short* __restrict__ W2,   // [64][576] bf16
    const float* __restrict__ wb, const float* __restrict__ bg,
    const float* __restrict__ bb, const float* __restrict__ bm,
    const float* __restrict__ bv, float* __restrict__ xout)
{
  const int NFT = (TV + 255) >> 8;  // 65
  const int n = blockIdx.x / NFT, ft = blockIdx.x % NFT;
  const int f0 = ft << 8;
  const int tid = threadIdx.x;
  const int w = tid >> 6, lane = tid & 63;
  const int l15 = lane & 15, l4 = lane >> 4;
  __shared__ unsigned short sIn[464 * 64];  // 59392 B

  const unsigned short* xb = xin + (size_t)n * CC * TV;
  for (int it = tid; it < 58 * 64; it += 256) {
    const int ci = it & 63, fc = it >> 6;   // fc 0..57
    const int flb = fc << 3;
    const int fg = f0 - 104 + flb;
    unsigned short e[8];
    if (fg >= 0 && fg + 8 <= TV) {
      const uint2 v0 = *(const uint2*)(xb + (size_t)ci * TV + fg);
      const uint2 v1 = *(const uint2*)(xb + (size_t)ci * TV + fg + 4);
      e[0] = (unsigned short)(v0.x & 0xffffu); e[1] = (unsigned short)(v0.x >> 16);
      e[2] = (unsigned short)(v0.y & 0xffffu); e[3] = (unsigned short)(v0.y >> 16);
      e[4] = (unsigned short)(v1.x & 0xffffu); e[5] = (unsigned short)(v1.x >> 16);
      e[6] = (unsigned short)(v1.y & 0xffffu); e[7] = (unsigned short)(v1.y >> 16);
    } else {
      #pragma unroll
      for (int j = 0; j < 8; ++j) {
        const int f = fg + j;
        e[j] = (f >= 0 && f < TV) ? xb[(size_t)ci * TV + f] : (unsigned short)0;
      }
    }
    const int cg8 = ci >> 3, cl = ci & 7;
    #pragma unroll
    for (int j = 0; j < 8; ++j) {
      sIn[((flb + j) << 6) + ((cg8 ^ j) << 3) + cl] = e[j];
    }
  }
  __syncthreads();

  const int w64 = w << 6;
  f32x4 acc[4][4] = {};
  short8 aCur[4], aNxt[4];
  {
    const int koff = (l4 << 3);
    #pragma unroll
    for (int mt = 0; mt < 4; ++mt)
      aCur[mt] = *(const short8*)(W2 + (size_t)(mt * 16 + l15) * 576 + koff);
  }
  for (int s = 0; s < 18; ++s) {
    if (s < 17) {
      const int s1 = s + 1;
      const int koff = ((s1 >> 1) << 6) + ((s1 & 1) << 5) + (l4 << 3);
      #pragma unroll
      for (int mt = 0; mt < 4; ++mt)
        aNxt[mt] = *(const short8*)(W2 + (size_t)(mt * 16 + l15) * 576 + koff);
    }
    const int dt = s >> 1;
    const int cg = ((s & 1) << 2) + l4;
    const int flb = w64 + l15 + (dt - 4) * 26 + 104;
    short8 bfrag[4];
    #pragma unroll
    for (int nt = 0; nt < 4; ++nt) {
      const int fl = flb + (nt << 4);
      bfrag[nt] = *(const short8*)&sIn[(fl << 6) + ((cg ^ (fl & 7)) << 3)];
    }
    #pragma unroll
    for (int mt = 0; mt < 4; ++mt)
      #pragma unroll
      for (int nt = 0; nt < 4; ++nt)
        acc[mt][nt] = __builtin_amdgcn_mfma_f32_16x16x32_bf16(
            aCur[mt], bfrag[nt], acc[mt][nt], 0, 0, 0);
    if (s < 17) {
      #pragma unroll
      for (int mt = 0; mt < 4; ++mt) aCur[mt] = aNxt[mt];
    }
  }

  float* ob = xout + (size_t)n * CC * TV;
  #pragma unroll
  for (int mt = 0; mt < 4; ++mt) {
    #pragma unroll
    for (int r = 0; r < 4; ++r) {
      const int c = mt * 16 + (l4 << 2) + r;
      const float sc = bg[c] * rsqrtf(bv[c] + EPS);
      const float off = fmaf(wb[c] - bm[c], sc, bb[c]);
      #pragma unroll
      for (int nt = 0; nt < 4; ++nt) {
        const int f = f0 + w64 + (nt << 4) + l15;
        if (f < TV)
          ob[(size_t)c * TV + f] = fmaxf(fmaf(acc[mt][nt][r], sc, off), 0.f);
      }
    }
  }
}

// ---------------------------------------------------------------------------
// K3a: pooled / per-v T-mean  (unchanged)
// ---------------------------------------------------------------------------
__global__ __launch_bounds__(256) void k_pool(
    const float* __restrict__ h, float* __restrict__ pooled,
    float* __restrict__ hmeanv)
{
  const int tid = threadIdx.x;
  const int bid = blockIdx.x;
  const float* row = h + (size_t)bid * TV;
  __shared__ float part[9 * VV];
  if (tid < 9 * VV) {
    const int tt = tid / VV, v = tid - tt * VV;
    float s = 0.f;
    for (int t = tt; t < TT_; t += 9) s += row[t * VV + v];
    part[tid] = s;
  }
  __syncthreads();
  if (tid < VV) {
    float tot = 0.f;
    #pragma unroll
    for (int j = 0; j < 9; ++j) tot += part[j * VV + tid];
    hmeanv[(size_t)bid * VV + tid] = tot / (float)TT_;
    part[tid] = tot;
  }
  __syncthreads();
  if (tid == 0) {
    float tot = 0.f;
    for (int v = 0; v < VV; ++v) tot += part[v];
    pooled[bid] = tot / (float)TV;
  }
}

// ---------------------------------------------------------------------------
// K3b: per-n head  (unchanged)
// ---------------------------------------------------------------------------
__global__ __launch_bounds__(256) void k_head_edge(
    const float* __restrict__ pooled, const float* __restrict__ hmeanv,
    const float* __restrict__ fcw, const float* __restrict__ fcb,
    const float* __restrict__ ag, const float* __restrict__ ab,
    const float* __restrict__ am, const float* __restrict__ av,
    const float* __restrict__ attw, const float* __restrict__ edgew,
    const float* __restrict__ eg, const float* __restrict__ eb,
    const float* __restrict__ em, const float* __restrict__ ev,
    float* __restrict__ dout)
{
  const int tid = threadIdx.x;
  const int n = blockIdx.x;
  __shared__ float sbnm[CC * VV];
  __shared__ float sxam[NCLS * VV];
  __shared__ float spool[CC];
  for (int i = tid; i < CC * VV; i += 256) {
    const int c = i / VV;
    const float s = ag[c] * rsqrtf(av[c] + EPS);
    const float off = ab[c] - am[c] * s;
    sbnm[i] = fmaf(hmeanv[(size_t)(n * CC) * VV + i], s, off);
  }
  if (tid < CC) spool[tid] = pooled[n * CC + tid];
  __syncthreads();
  for (int i = tid; i < NCLS * VV; i += 256) {
    const int o = i / VV, v = i - o * VV;
    float a = 0.f;
    for (int c = 0; c < CC; ++c) a = fmaf(attw[o * CC + c], sbnm[c * VV + v], a);
    sxam[i] = a;
  }
  if (tid < NCLS) {
    float a = fcb[tid];
    for (int c = 0; c < CC; ++c) a = fmaf(spool[c], fcw[tid * CC + c], a);
    dout[n * NCLS + tid] = a;
  }
  __syncthreads();
  for (int i = tid; i < NAE * VV * VV; i += 256) {
    const int j = i / VV, v = i - j * VV;
    float a = 0.f;
    for (int o = 0; o < NCLS; ++o) a = fmaf(edgew[j * NCLS + o], sxam[o * VV + v], a);
    const float s = eg[j] * rsqrtf(ev[j] + EPS);
    const float val = tanhf(fmaf(a - em[j], s, eb[j]));
    dout[NN * NCLS + (size_t)NN * TV + (size_t)n * NAE * VV * VV + i] = fmaxf(val, 0.f);
  }
}

// ---------------------------------------------------------------------------
// K3c: node attention  (unchanged)
// ---------------------------------------------------------------------------
__global__ __launch_bounds__(256) void k_node(
    const float* __restrict__ h,
    const float* __restrict__ ag, const float* __restrict__ ab,
    const float* __restrict__ am, const float* __restrict__ av,
    const float* __restrict__ attw, const float* __restrict__ nodew,
    const float* __restrict__ ng, const float* __restrict__ nb,
    const float* __restrict__ nm, const float* __restrict__ nv,
    float* __restrict__ dout)
{
  const int tid = threadIdx.x;
  __shared__ float ac[CC];
  __shared__ float tmp[CC];
  if (tid < CC) {
    float nc = 0.f;
    for (int o = 0; o < NCLS; ++o) nc = fmaf(nodew[o], attw[o * CC + tid], nc);
    const float s = ag[tid] * rsqrtf(av[tid] + EPS);
    const float off = ab[tid] - am[tid] * s;
    ac[tid] = nc * s;
    tmp[tid] = nc * off;
  }
  __syncthreads();
  if (tid == 0) {
    float b = 0.f;
    for (int c = 0; c < CC; ++c) b += tmp[c];
    tmp[0] = b;
  }
  __syncthreads();
  const float b0 = tmp[0];
  const size_t i = (size_t)blockIdx.x * 256 + tid;
  if (i < (size_t)NN * TV) {
    const int n = (int)(i / TV), f = (int)(i - (size_t)n * TV);
    const float* hb = h + (size_t)n * CC * TV + f;
    float xsum = b0;
    #pragma unroll 8
    for (int c = 0; c < CC; ++c) xsum = fmaf(hb[(size_t)c * TV], ac[c], xsum);
    const float s = ng[0] * rsqrtf(nv[0] + EPS);
    const float y = fmaf(xsum - nm[0], s, nb[0]);
    dout[NN * NCLS + i] = 1.f / (1.f + expf(-y));
  }
}

// ---------------------------------------------------------------------------
extern "C" void kernel_launch(void* const* d_in, const int* in_sizes, int n_in,
                              void* d_out, int out_size, void* d_ws, size_t ws_size,
                              hipStream_t stream) {
  const float* x        = (const float*)d_in[0];
  const float* A        = (const float*)d_in[1];
  const float* sgc_w    = (const float*)d_in[2];
  const float* sgc_b    = (const float*)d_in[3];
  const float* M        = (const float*)d_in[4];
  const float* bnA_g    = (const float*)d_in[5];
  const float* bnA_b    = (const float*)d_in[6];
  const float* bnA_m    = (const float*)d_in[7];
  const float* bnA_v    = (const float*)d_in[8];
  const float* tconv_w  = (const float*)d_in[9];
  const float* tconv_b  = (const float*)d_in[10];
  const float* bnB_g    = (const float*)d_in[11];
  const float* bnB_b    = (const float*)d_in[12];
  const float* bnB_m    = (const float*)d_in[13];
  const float* bnB_v    = (const float*)d_in[14];
  const float* fc_w     = (const float*)d_in[15];
  const float* fc_b     = (const float*)d_in[16];
  const float* attbn_g  = (const float*)d_in[17];
  const float* attbn_b  = (const float*)d_in[18];
  const float* attbn_m  = (const float*)d_in[19];
  const float* attbn_v  = (const float*)d_in[20];
  // d_in[21..34]: transformer branch params — dead code in the reference.
  const float* attconv_w  = (const float*)d_in[35];
  const float* nodeconv_w = (const float*)d_in[36];
  const float* nodebn_g   = (const float*)d_in[37];
  const float* nodebn_b   = (const float*)d_in[38];
  const float* nodebn_m   = (const float*)d_in[39];
  const float* nodebn_v   = (const float*)d_in[40];
  const float* edgeconv_w = (const float*)d_in[41];
  const float* edgebn_g   = (const float*)d_in[42];
  const float* edgebn_b   = (const float*)d_in[43];
  const float* edgebn_m   = (const float*)d_in[44];
  const float* edgebn_v   = (const float*)d_in[45];

  // workspace layout
  float* pooled = (float*)d_ws;                              // 1024 f32
  float* hmeanv = pooled + NN * CC;                          // 26624 f32
  unsigned short* W2 = (unsigned short*)(hmeanv + (size_t)NN * CC * VV);
  unsigned short* W1 = W2 + (size_t)CC * 576;                // 192*64 bf16
  unsigned short* bufA = W1 + (size_t)OO * CC;               // bf16 act
  float* bufB = (float*)(bufA + (size_t)NN * CC * TV);       // f32 act
  unsigned short* y1 = (unsigned short*)(bufB + (size_t)NN * CC * TV);
  float* out = (float*)d_out;

  const int NFT1 = (TV + 127) >> 7;  // 129 (pw MFMA)
  const int NTT  = (TT_ + 3) >> 2;   // 159
  const int NFC  = (TV + 255) >> 8;  // 65
  for (int i = 0; i < 3; ++i) {
    const float* src = (i == 0) ? x : bufB;
    k_prep_w1<<<(OO * CC + 255) / 256, 256, 0, stream>>>(
        sgc_w + (size_t)i * OO * CC, W1);
    k_prep_w2<<<(CC * 576 + 255) / 256, 256, 0, stream>>>(
        tconv_w + (size_t)i * CC * CC * TKK, W2);
    k_sgc_pw_mfma<<<NN * NFT1, 256, 0, stream>>>(
        src, W1, sgc_b + i * OO, y1);
    k_sgc_graph2<<<NN * NTT, 256, 0, stream>>>(
        y1, A, M + (size_t)i * KK * VV * VV,
        bnA_g + i * CC, bnA_b + i * CC, bnA_m + i * CC, bnA_v + i * CC,
        bufA, NN);
    k_tconv_mfma<<<NN * NFC, 256, 0, stream>>>(
        bufA, W2, tconv_b + i * CC,
        bnB_g + i * CC, bnB_b + i * CC, bnB_m + i * CC, bnB_v + i * CC, bufB);
  }
  k_pool<<<NN * CC, 256, 0, stream>>>(bufB, pooled, hmeanv);
  k_head_edge<<<NN, 256, 0, stream>>>(pooled, hmeanv, fc_w, fc_b,
      attbn_g, attbn_b, attbn_m, attbn_v, attconv_w, edgeconv_w,
      edgebn_g, edgebn_b, edgebn_m, edgebn_v, out);
  k_node<<<((size_t)NN * TV + 255) / 256, 256, 0, stream>>>(
      bufB, attbn_g, attbn_b, attbn_m, attbn_v, attconv_w, nodeconv_w,
      nodebn_g, nodebn_b, nodebn_m, nodebn_v, out);
}

// Round 6
// 831.212 us; speedup vs baseline: 3.2949x; 1.3126x over previous
//
#include <hip/hip_runtime.h>
#include <hip/hip_bf16.h>
#include <math.h>

#define NN 16
#define CC 64
#define TT_ 634
#define VV 26
#define TV 16484      // TT_*VV
#define KK 3
#define OO 192        // KK*CC
#define TKK 9
#define NCLS 60
#define NAE 4
#define EPS 1e-5f

typedef __attribute__((ext_vector_type(8))) short short8;
typedef __attribute__((ext_vector_type(4))) float f32x4;

static __device__ __forceinline__ float bf2f(unsigned int u) {
  union { unsigned int i; float f; } v; v.i = u << 16; return v.f;
}
static __device__ __forceinline__ unsigned int f2bf(float x) {
  union { float f; unsigned int i; } v; v.f = x;
  unsigned int r = v.i + 0x7fffu + ((v.i >> 16) & 1u);
  return r >> 16;
}

#define W1_ELEMS (3 * OO * CC)     // 36864
#define W2_ELEMS (3 * CC * 576)    // 110592
#define AM_ELEMS (3 * KK * 1024)   // 9216

// ---------------------------------------------------------------------------
// Prep (once): all 3 layers' weights -> bf16.
//  W1all[i][o][ci]           = sgc_w (flat convert, already k-contiguous)
//  W2all[i][c][dt*64+ci]     = tconv_w[i][c][ci][dt]
//  AMall[i][k][w][v] (32x32) = A[k][v][w]*M[i][k][v][w], zero-padded v,w>=26
// ---------------------------------------------------------------------------
__global__ __launch_bounds__(256) void k_prep_all(
    const float* __restrict__ sgc_w, const float* __restrict__ tconv_w,
    const float* __restrict__ Ap, const float* __restrict__ Mp,
    unsigned short* __restrict__ W1all, unsigned short* __restrict__ W2all,
    unsigned short* __restrict__ AMall)
{
  int j = blockIdx.x * 256 + threadIdx.x;
  if (j < W1_ELEMS) { W1all[j] = (unsigned short)f2bf(sgc_w[j]); return; }
  j -= W1_ELEMS;
  if (j < W2_ELEMS) {
    const int i = j / (CC * 576), r = j % (CC * 576);
    const int c = r / 576, q = r % 576, dt = q >> 6, ci = q & 63;
    W2all[j] = (unsigned short)f2bf(
        tconv_w[(size_t)i * CC * CC * TKK + c * 576 + ci * 9 + dt]);
    return;
  }
  j -= W2_ELEMS;
  if (j < AM_ELEMS) {
    const int i = j / (KK * 1024), r = j % (KK * 1024);
    const int k = r >> 10, rr = r & 1023;
    const int w = rr >> 5, v = rr & 31;
    float val = 0.f;
    if (w < VV && v < VV)
      val = Ap[(k * VV + v) * VV + w] *
            Mp[((size_t)i * KK + k) * VV * VV + v * VV + w];
    AMall[j] = (unsigned short)f2bf(val);
  }
}

// ---------------------------------------------------------------------------
// S1 (MFMA): y1[n][o][f] (bf16) = sum_ci W[o][ci] * h[n][ci][f] + Wb[o]
// (unchanged from R5 — validated)
// ---------------------------------------------------------------------------
__global__ __launch_bounds__(256) void k_sgc_pw_mfma(
    const float* __restrict__ hin,          // [16][64][TV] f32
    const unsigned short* __restrict__ W1,  // [192][64] bf16
    const float* __restrict__ Wb,           // [192]
    unsigned short* __restrict__ y1)        // [16][192][TV] bf16
{
  const int NFT = (TV + 127) >> 7;  // 129
  const int n = blockIdx.x / NFT, ft = blockIdx.x % NFT;
  const int f0 = ft << 7;
  const int tid = threadIdx.x;
  const int w = tid >> 6, lane = tid & 63;
  const int l15 = lane & 15, l4 = lane >> 4;
  const int m0 = (w >> 1) * 96;    // 0 or 96
  const int n0 = (w & 1) * 64;     // 0 or 64
  __shared__ unsigned short sIn[128 * 64];  // 16 KB, [f][ci] swizzled

  const float* hb = hin + (size_t)n * CC * TV;
  for (int it = tid; it < 16 * 64; it += 256) {
    const int ci = it & 63, fc = it >> 6;   // fc 0..15
    const int flb = fc << 3;
    const int fg = f0 + flb;
    float e[8];
    if (fg + 8 <= TV) {
      const float4 v0 = *(const float4*)(hb + (size_t)ci * TV + fg);
      const float4 v1 = *(const float4*)(hb + (size_t)ci * TV + fg + 4);
      e[0] = v0.x; e[1] = v0.y; e[2] = v0.z; e[3] = v0.w;
      e[4] = v1.x; e[5] = v1.y; e[6] = v1.z; e[7] = v1.w;
    } else {
      #pragma unroll
      for (int j = 0; j < 8; ++j) {
        const int f = fg + j;
        e[j] = (f < TV) ? hb[(size_t)ci * TV + f] : 0.f;
      }
    }
    const int cg8 = ci >> 3, cl = ci & 7;
    #pragma unroll
    for (int j = 0; j < 8; ++j) {
      sIn[((flb + j) << 6) + (((cg8 ^ j)) << 3) + cl] = (unsigned short)f2bf(e[j]);
    }
  }
  __syncthreads();

  short8 afr[2][6];
  #pragma unroll
  for (int ks = 0; ks < 2; ++ks)
    #pragma unroll
    for (int mf = 0; mf < 6; ++mf) {
      const int o = m0 + mf * 16 + l15;
      afr[ks][mf] = *(const short8*)(W1 + (size_t)o * CC + (ks << 5) + (l4 << 3));
    }

  f32x4 acc[6][4] = {};
  #pragma unroll
  for (int ks = 0; ks < 2; ++ks) {
    short8 bfr[4];
    const int cg = (ks << 2) + l4;
    #pragma unroll
    for (int nf = 0; nf < 4; ++nf) {
      const int fl = n0 + (nf << 4) + l15;
      bfr[nf] = *(const short8*)&sIn[(fl << 6) + ((cg ^ (fl & 7)) << 3)];
    }
    #pragma unroll
    for (int mf = 0; mf < 6; ++mf)
      #pragma unroll
      for (int nf = 0; nf < 4; ++nf)
        acc[mf][nf] = __builtin_amdgcn_mfma_f32_16x16x32_bf16(
            afr[ks][mf], bfr[nf], acc[mf][nf], 0, 0, 0);
  }

  unsigned short* yb = y1 + (size_t)n * OO * TV;
  #pragma unroll
  for (int mf = 0; mf < 6; ++mf) {
    #pragma unroll
    for (int r = 0; r < 4; ++r) {
      const int o = m0 + mf * 16 + (l4 << 2) + r;
      const float bias = Wb[o];
      #pragma unroll
      for (int nf = 0; nf < 4; ++nf) {
        const int f = f0 + n0 + (nf << 4) + l15;
        if (f < TV)
          yb[(size_t)o * TV + f] = (unsigned short)f2bf(acc[mf][nf][r] + bias);
      }
    }
  }
}

// ---------------------------------------------------------------------------
// S2 (MFMA, no LDS): h[n][c][t][w] = relu(bnA( sum_{k,v} y1[k64+c][t][v]
//                                              * AM[k][v][w] ))
// Batched GEMM per (n,c): M=t (16-tiles), N=w (2 tiles), K=(k,v) padded 3x32.
// A-frag = contiguous 16B global load from y1 (v-tail garbage killed by
// B-side zeros). B-frags (AMbf[k][w][v], 6KB L2) hoisted out of t-loop.
// grid = NN*CC blocks x 4 waves; each wave owns 10 t-tiles.
// ---------------------------------------------------------------------------
__global__ __launch_bounds__(256) void k_graph_mfma(
    const unsigned short* __restrict__ y1,   // [16][192][TV] bf16
    const unsigned short* __restrict__ AMk,  // [KK][32][32] bf16 layer slice
    const float* __restrict__ bg, const float* __restrict__ bb,
    const float* __restrict__ bm, const float* __restrict__ bv,
    unsigned short* __restrict__ hout)       // [16][64][TV] bf16
{
  const int n = blockIdx.x >> 6, c = blockIdx.x & 63;
  const int tid = threadIdx.x;
  const int w = tid >> 6, lane = tid & 63;
  const int l15 = lane & 15, l4 = lane >> 4;

  short8 bf[KK][2];
  #pragma unroll
  for (int k = 0; k < KK; ++k)
    #pragma unroll
    for (int wt = 0; wt < 2; ++wt)
      bf[k][wt] = *(const short8*)(AMk + (k << 10) + ((wt * 16 + l15) << 5)
                                   + (l4 << 3));

  const float s = bg[c] * rsqrtf(bv[c] + EPS);
  const float off = bb[c] - bm[c] * s;
  const unsigned short* yb = y1 + (size_t)n * OO * TV;
  unsigned short* ob = hout + ((size_t)n * CC + c) * TV;

  for (int i = 0; i < 10; ++i) {
    const int t0 = (w * 10 + i) << 4;
    const int tr = t0 + l15;
    int eoff = tr * VV + (l4 << 3);
    eoff = eoff > (TV - 8) ? (TV - 8) : eoff;
    short8 af[KK];
    #pragma unroll
    for (int k = 0; k < KK; ++k)
      af[k] = *(const short8*)(yb + (size_t)(k * CC + c) * TV + eoff);
    f32x4 acc0 = {}, acc1 = {};
    #pragma unroll
    for (int k = 0; k < KK; ++k) {
      acc0 = __builtin_amdgcn_mfma_f32_16x16x32_bf16(af[k], bf[k][0], acc0, 0, 0, 0);
      acc1 = __builtin_amdgcn_mfma_f32_16x16x32_bf16(af[k], bf[k][1], acc1, 0, 0, 0);
    }
    #pragma unroll
    for (int r = 0; r < 4; ++r) {
      const int t = t0 + (l4 << 2) + r;
      if (t < TT_) {
        const float v0 = fmaxf(fmaf(acc0[r], s, off), 0.f);
        ob[t * VV + l15] = (unsigned short)f2bf(v0);
        if (l15 < 10) {
          const float v1 = fmaxf(fmaf(acc1[r], s, off), 0.f);
          ob[t * VV + 16 + l15] = (unsigned short)f2bf(v1);
        }
      }
    }
  }
}

// ---------------------------------------------------------------------------
// K2 (MFMA): temporal conv  (unchanged from R4 — validated)
// ---------------------------------------------------------------------------
__global__ __launch_bounds__(256) void k_tconv_mfma(
    const unsigned short* __restrict__ xin,  // [16][64][TV] bf16
    const unsigned short* __restrict__ W2,   // [64][576] bf16
    const float* __restrict__ wb, const float* __restrict__ bg,
    const float* __restrict__ bb, const float* __restrict__ bm,
    const float* __restrict__ bv, float* __restrict__ xout)
{
  const int NFT = (TV + 255) >> 8;  // 65
  const int n = blockIdx.x / NFT, ft = blockIdx.x % NFT;
  const int f0 = ft << 8;
  const int tid = threadIdx.x;
  const int w = tid >> 6, lane = tid & 63;
  const int l15 = lane & 15, l4 = lane >> 4;
  __shared__ unsigned short sIn[464 * 64];  // 59392 B

  const unsigned short* xb = xin + (size_t)n * CC * TV;
  for (int it = tid; it < 58 * 64; it += 256) {
    const int ci = it & 63, fc = it >> 6;   // fc 0..57
    const int flb = fc << 3;
    const int fg = f0 - 104 + flb;
    unsigned short e[8];
    if (fg >= 0 && fg + 8 <= TV) {
      const uint2 v0 = *(const uint2*)(xb + (size_t)ci * TV + fg);
      const uint2 v1 = *(const uint2*)(xb + (size_t)ci * TV + fg + 4);
      e[0] = (unsigned short)(v0.x & 0xffffu); e[1] = (unsigned short)(v0.x >> 16);
      e[2] = (unsigned short)(v0.y & 0xffffu); e[3] = (unsigned short)(v0.y >> 16);
      e[4] = (unsigned short)(v1.x & 0xffffu); e[5] = (unsigned short)(v1.x >> 16);
      e[6] = (unsigned short)(v1.y & 0xffffu); e[7] = (unsigned short)(v1.y >> 16);
    } else {
      #pragma unroll
      for (int j = 0; j < 8; ++j) {
        const int f = fg + j;
        e[j] = (f >= 0 && f < TV) ? xb[(size_t)ci * TV + f] : (unsigned short)0;
      }
    }
    const int cg8 = ci >> 3, cl = ci & 7;
    #pragma unroll
    for (int j = 0; j < 8; ++j) {
      sIn[((flb + j) << 6) + ((cg8 ^ j) << 3) + cl] = e[j];
    }
  }
  __syncthreads();

  const int w64 = w << 6;
  f32x4 acc[4][4] = {};
  short8 aCur[4], aNxt[4];
  {
    const int koff = (l4 << 3);
    #pragma unroll
    for (int mt = 0; mt < 4; ++mt)
      aCur[mt] = *(const short8*)(W2 + (size_t)(mt * 16 + l15) * 576 + koff);
  }
  for (int s = 0; s < 18; ++s) {
    if (s < 17) {
      const int s1 = s + 1;
      const int koff = ((s1 >> 1) << 6) + ((s1 & 1) << 5) + (l4 << 3);
      #pragma unroll
      for (int mt = 0; mt < 4; ++mt)
        aNxt[mt] = *(const short8*)(W2 + (size_t)(mt * 16 + l15) * 576 + koff);
    }
    const int dt = s >> 1;
    const int cg = ((s & 1) << 2) + l4;
    const int flb = w64 + l15 + (dt - 4) * 26 + 104;
    short8 bfrag[4];
    #pragma unroll
    for (int nt = 0; nt < 4; ++nt) {
      const int fl = flb + (nt << 4);
      bfrag[nt] = *(const short8*)&sIn[(fl << 6) + ((cg ^ (fl & 7)) << 3)];
    }
    #pragma unroll
    for (int mt = 0; mt < 4; ++mt)
      #pragma unroll
      for (int nt = 0; nt < 4; ++nt)
        acc[mt][nt] = __builtin_amdgcn_mfma_f32_16x16x32_bf16(
            aCur[mt], bfrag[nt], acc[mt][nt], 0, 0, 0);
    if (s < 17) {
      #pragma unroll
      for (int mt = 0; mt < 4; ++mt) aCur[mt] = aNxt[mt];
    }
  }

  float* ob = xout + (size_t)n * CC * TV;
  #pragma unroll
  for (int mt = 0; mt < 4; ++mt) {
    #pragma unroll
    for (int r = 0; r < 4; ++r) {
      const int c = mt * 16 + (l4 << 2) + r;
      const float sc = bg[c] * rsqrtf(bv[c] + EPS);
      const float off = fmaf(wb[c] - bm[c], sc, bb[c]);
      #pragma unroll
      for (int nt = 0; nt < 4; ++nt) {
        const int f = f0 + w64 + (nt << 4) + l15;
        if (f < TV)
          ob[(size_t)c * TV + f] = fmaxf(fmaf(acc[mt][nt][r], sc, off), 0.f);
      }
    }
  }
}

// ---------------------------------------------------------------------------
// K3a: pooled / per-v T-mean  (unchanged)
// ---------------------------------------------------------------------------
__global__ __launch_bounds__(256) void k_pool(
    const float* __restrict__ h, float* __restrict__ pooled,
    float* __restrict__ hmeanv)
{
  const int tid = threadIdx.x;
  const int bid = blockIdx.x;
  const float* row = h + (size_t)bid * TV;
  __shared__ float part[9 * VV];
  if (tid < 9 * VV) {
    const int tt = tid / VV, v = tid - tt * VV;
    float s = 0.f;
    for (int t = tt; t < TT_; t += 9) s += row[t * VV + v];
    part[tid] = s;
  }
  __syncthreads();
  if (tid < VV) {
    float tot = 0.f;
    #pragma unroll
    for (int j = 0; j < 9; ++j) tot += part[j * VV + tid];
    hmeanv[(size_t)bid * VV + tid] = tot / (float)TT_;
    part[tid] = tot;
  }
  __syncthreads();
  if (tid == 0) {
    float tot = 0.f;
    for (int v = 0; v < VV; ++v) tot += part[v];
    pooled[bid] = tot / (float)TV;
  }
}

// ---------------------------------------------------------------------------
// K3b: per-n head  (unchanged)
// ---------------------------------------------------------------------------
__global__ __launch_bounds__(256) void k_head_edge(
    const float* __restrict__ pooled, const float* __restrict__ hmeanv,
    const float* __restrict__ fcw, const float* __restrict__ fcb,
    const float* __restrict__ ag, const float* __restrict__ ab,
    const float* __restrict__ am, const float* __restrict__ av,
    const float* __restrict__ attw, const float* __restrict__ edgew,
    const float* __restrict__ eg, const float* __restrict__ eb,
    const float* __restrict__ em, const float* __restrict__ ev,
    float* __restrict__ dout)
{
  const int tid = threadIdx.x;
  const int n = blockIdx.x;
  __shared__ float sbnm[CC * VV];
  __shared__ float sxam[NCLS * VV];
  __shared__ float spool[CC];
  for (int i = tid; i < CC * VV; i += 256) {
    const int c = i / VV;
    const float s = ag[c] * rsqrtf(av[c] + EPS);
    const float off = ab[c] - am[c] * s;
    sbnm[i] = fmaf(hmeanv[(size_t)(n * CC) * VV + i], s, off);
  }
  if (tid < CC) spool[tid] = pooled[n * CC + tid];
  __syncthreads();
  for (int i = tid; i < NCLS * VV; i += 256) {
    const int o = i / VV, v = i - o * VV;
    float a = 0.f;
    for (int c = 0; c < CC; ++c) a = fmaf(attw[o * CC + c], sbnm[c * VV + v], a);
    sxam[i] = a;
  }
  if (tid < NCLS) {
    float a = fcb[tid];
    for (int c = 0; c < CC; ++c) a = fmaf(spool[c], fcw[tid * CC + c], a);
    dout[n * NCLS + tid] = a;
  }
  __syncthreads();
  for (int i = tid; i < NAE * VV * VV; i += 256) {
    const int j = i / VV, v = i - j * VV;
    float a = 0.f;
    for (int o = 0; o < NCLS; ++o) a = fmaf(edgew[j * NCLS + o], sxam[o * VV + v], a);
    const float s = eg[j] * rsqrtf(ev[j] + EPS);
    const float val = tanhf(fmaf(a - em[j], s, eb[j]));
    dout[NN * NCLS + (size_t)NN * TV + (size_t)n * NAE * VV * VV + i] = fmaxf(val, 0.f);
  }
}

// ---------------------------------------------------------------------------
// K3c: node attention  (unchanged)
// ---------------------------------------------------------------------------
__global__ __launch_bounds__(256) void k_node(
    const float* __restrict__ h,
    const float* __restrict__ ag, const float* __restrict__ ab,
    const float* __restrict__ am, const float* __restrict__ av,
    const float* __restrict__ attw, const float* __restrict__ nodew,
    const float* __restrict__ ng, const float* __restrict__ nb,
    const float* __restrict__ nm, const float* __restrict__ nv,
    float* __restrict__ dout)
{
  const int tid = threadIdx.x;
  __shared__ float ac[CC];
  __shared__ float tmp[CC];
  if (tid < CC) {
    float nc = 0.f;
    for (int o = 0; o < NCLS; ++o) nc = fmaf(nodew[o], attw[o * CC + tid], nc);
    const float s = ag[tid] * rsqrtf(av[tid] + EPS);
    const float off = ab[tid] - am[tid] * s;
    ac[tid] = nc * s;
    tmp[tid] = nc * off;
  }
  __syncthreads();
  if (tid == 0) {
    float b = 0.f;
    for (int c = 0; c < CC; ++c) b += tmp[c];
    tmp[0] = b;
  }
  __syncthreads();
  const float b0 = tmp[0];
  const size_t i = (size_t)blockIdx.x * 256 + tid;
  if (i < (size_t)NN * TV) {
    const int n = (int)(i / TV), f = (int)(i - (size_t)n * TV);
    const float* hb = h + (size_t)n * CC * TV + f;
    float xsum = b0;
    #pragma unroll 8
    for (int c = 0; c < CC; ++c) xsum = fmaf(hb[(size_t)c * TV], ac[c], xsum);
    const float s = ng[0] * rsqrtf(nv[0] + EPS);
    const float y = fmaf(xsum - nm[0], s, nb[0]);
    dout[NN * NCLS + i] = 1.f / (1.f + expf(-y));
  }
}

// ---------------------------------------------------------------------------
extern "C" void kernel_launch(void* const* d_in, const int* in_sizes, int n_in,
                              void* d_out, int out_size, void* d_ws, size_t ws_size,
                              hipStream_t stream) {
  const float* x        = (const float*)d_in[0];
  const float* A        = (const float*)d_in[1];
  const float* sgc_w    = (const float*)d_in[2];
  const float* sgc_b    = (const float*)d_in[3];
  const float* M        = (const float*)d_in[4];
  const float* bnA_g    = (const float*)d_in[5];
  const float* bnA_b    = (const float*)d_in[6];
  const float* bnA_m    = (const float*)d_in[7];
  const float* bnA_v    = (const float*)d_in[8];
  const float* tconv_w  = (const float*)d_in[9];
  const float* tconv_b  = (const float*)d_in[10];
  const float* bnB_g    = (const float*)d_in[11];
  const float* bnB_b    = (const float*)d_in[12];
  const float* bnB_m    = (const float*)d_in[13];
  const float* bnB_v    = (const float*)d_in[14];
  const float* fc_w     = (const float*)d_in[15];
  const float* fc_b     = (const float*)d_in[16];
  const float* attbn_g  = (const float*)d_in[17];
  const float* attbn_b  = (const float*)d_in[18];
  const float* attbn_m  = (const float*)d_in[19];
  const float* attbn_v  = (const float*)d_in[20];
  // d_in[21..34]: transformer branch params — dead code in the reference.
  const float* attconv_w  = (const float*)d_in[35];
  const float* nodeconv_w = (const float*)d_in[36];
  const float* nodebn_g   = (const float*)d_in[37];
  const float* nodebn_b   = (const float*)d_in[38];
  const float* nodebn_m   = (const float*)d_in[39];
  const float* nodebn_v   = (const float*)d_in[40];
  const float* edgeconv_w = (const float*)d_in[41];
  const float* edgebn_g   = (const float*)d_in[42];
  const float* edgebn_b   = (const float*)d_in[43];
  const float* edgebn_m   = (const float*)d_in[44];
  const float* edgebn_v   = (const float*)d_in[45];

  // workspace layout
  float* pooled = (float*)d_ws;                              // 1024 f32
  float* hmeanv = pooled + NN * CC;                          // 26624 f32
  unsigned short* W1all = (unsigned short*)(hmeanv + (size_t)NN * CC * VV);
  unsigned short* W2all = W1all + W1_ELEMS;
  unsigned short* AMall = W2all + W2_ELEMS;
  unsigned short* bufA  = AMall + AM_ELEMS;                  // bf16 act
  float* bufB = (float*)(bufA + (size_t)NN * CC * TV);       // f32 act
  unsigned short* y1 = (unsigned short*)(bufB + (size_t)NN * CC * TV);
  float* out = (float*)d_out;

  const int PREP_TOT = W1_ELEMS + W2_ELEMS + AM_ELEMS;
  k_prep_all<<<(PREP_TOT + 255) / 256, 256, 0, stream>>>(
      sgc_w, tconv_w, A, M, W1all, W2all, AMall);

  const int NFT1 = (TV + 127) >> 7;  // 129 (pw MFMA)
  const int NFC  = (TV + 255) >> 8;  // 65
  for (int i = 0; i < 3; ++i) {
    const float* src = (i == 0) ? x : bufB;
    k_sgc_pw_mfma<<<NN * NFT1, 256, 0, stream>>>(
        src, W1all + (size_t)i * OO * CC, sgc_b + i * OO, y1);
    k_graph_mfma<<<NN * CC, 256, 0, stream>>>(
        y1, AMall + (size_t)i * KK * 1024,
        bnA_g + i * CC, bnA_b + i * CC, bnA_m + i * CC, bnA_v + i * CC, bufA);
    k_tconv_mfma<<<NN * NFC, 256, 0, stream>>>(
        bufA, W2all + (size_t)i * CC * 576, tconv_b + i * CC,
        bnB_g + i * CC, bnB_b + i * CC, bnB_m + i * CC, bnB_v + i * CC, bufB);
  }
  k_pool<<<NN * CC, 256, 0, stream>>>(bufB, pooled, hmeanv);
  k_head_edge<<<NN, 256, 0, stream>>>(pooled, hmeanv, fc_w, fc_b,
      attbn_g, attbn_b, attbn_m, attbn_v, attconv_w, edgeconv_w,
      edgebn_g, edgebn_b, edgebn_m, edgebn_v, out);
  k_node<<<((size_t)NN * TV + 255) / 256, 256, 0, stream>>>(
      bufB, attbn_g, attbn_b, attbn_m, attbn_v, attconv_w, nodeconv_w,
      nodebn_g, nodebn_b, nodebn_m, nodebn_v, out);
}

// Round 8
// 632.986 us; speedup vs baseline: 4.3268x; 1.3132x over previous
//
#include <hip/hip_runtime.h>
#include <hip/hip_bf16.h>
#include <math.h>

#define NN 16
#define CC 64
#define TT_ 634
#define VV 26
#define TV 16484      // TT_*VV
#define KK 3
#define OO 192        // KK*CC
#define TKK 9
#define NCLS 60
#define NAE 4
#define EPS 1e-5f

typedef __attribute__((ext_vector_type(8))) short short8;
typedef __attribute__((ext_vector_type(4))) float f32x4;

static __device__ __forceinline__ float bf2f(unsigned int u) {
  union { unsigned int i; float f; } v; v.i = u << 16; return v.f;
}
static __device__ __forceinline__ unsigned int f2bf(float x) {
  union { float f; unsigned int i; } v; v.f = x;
  unsigned int r = v.i + 0x7fffu + ((v.i >> 16) & 1u);
  return r >> 16;
}

#define W1_ELEMS (3 * OO * CC)     // 36864
#define W2_ELEMS (3 * CC * 576)    // 110592
#define AM_ELEMS (3 * KK * 1024)   // 9216

// ---------------------------------------------------------------------------
// Prep (once): all 3 layers' weights -> bf16.  (validated R6)
// ---------------------------------------------------------------------------
__global__ __launch_bounds__(256) void k_prep_all(
    const float* __restrict__ sgc_w, const float* __restrict__ tconv_w,
    const float* __restrict__ Ap, const float* __restrict__ Mp,
    unsigned short* __restrict__ W1all, unsigned short* __restrict__ W2all,
    unsigned short* __restrict__ AMall)
{
  int j = blockIdx.x * 256 + threadIdx.x;
  if (j < W1_ELEMS) { W1all[j] = (unsigned short)f2bf(sgc_w[j]); return; }
  j -= W1_ELEMS;
  if (j < W2_ELEMS) {
    const int i = j / (CC * 576), r = j % (CC * 576);
    const int c = r / 576, q = r % 576, dt = q >> 6, ci = q & 63;
    W2all[j] = (unsigned short)f2bf(
        tconv_w[(size_t)i * CC * CC * TKK + c * 576 + ci * 9 + dt]);
    return;
  }
  j -= W2_ELEMS;
  if (j < AM_ELEMS) {
    const int i = j / (KK * 1024), r = j % (KK * 1024);
    const int k = r >> 10, rr = r & 1023;
    const int w = rr >> 5, v = rr & 31;
    float val = 0.f;
    if (w < VV && v < VV)
      val = Ap[(k * VV + v) * VV + w] *
            Mp[((size_t)i * KK + k) * VV * VV + v * VV + w];
    AMall[j] = (unsigned short)f2bf(val);
  }
}

// ---------------------------------------------------------------------------
// Fused SGC: pw-conv (GEMM1) + graph contraction (GEMM2) + bnA + relu.
// Block = (n, 4-t tile).  y1 lives only in LDS (sY) — no HBM round trip.
// GEMM1: M=192 o, N=112 f, K=64 ci (waves split M 4x48). sH staging/frags
//        identical to the validated pw kernel.
// GEMM2: per wave = one t. M=64 c, N=26 w, K=26 v (padded 32). A from sY
//        (4xb32: 26-col offsets not 16B aligned), B = AMall[k][w][v] with
//        v>=26 zeros killing cross-t garbage. sY cols <112 all written.
// ---------------------------------------------------------------------------
template<int F32IN>
__global__ __launch_bounds__(256) void k_fused_sgc(
    const void* __restrict__ hin,           // [16][64][TV] f32 or bf16
    const unsigned short* __restrict__ W1,  // [192][64] bf16 layer slice
    const float* __restrict__ Wb,           // [192]
    const unsigned short* __restrict__ AMk, // [KK][32][32] bf16 layer slice
    const float* __restrict__ bg, const float* __restrict__ bb,
    const float* __restrict__ bm, const float* __restrict__ bv,
    unsigned short* __restrict__ hout)      // [16][64][TV] bf16
{
  const int NTT = 159;
  const int n = blockIdx.x / NTT, tt = blockIdx.x % NTT;
  const int t0 = tt << 2;
  const int f0 = t0 * VV;
  const int tid = threadIdx.x;
  const int wv = tid >> 6, lane = tid & 63;
  const int l15 = lane & 15, l4 = lane >> 4;

  __shared__ unsigned short sH[112 * 64];   // 14336 B, [f][ci] swizzled
  __shared__ unsigned short sY[192 * 120];  // 46080 B, [o][f] pitch 120
  __shared__ float sWb[OO];
  __shared__ float sS[CC], sOff[CC];

  // GEMM2 B-frags (AM table, 6 KB L2) — hoisted
  short8 amf[KK][2];
  #pragma unroll
  for (int k = 0; k < KK; ++k)
    #pragma unroll
    for (int nf = 0; nf < 2; ++nf)
      amf[k][nf] = *(const short8*)(AMk + (k << 10) + ((nf * 16 + l15) << 5)
                                    + (l4 << 3));

  // GEMM1 A-frags (W1, 24 KB L2)
  const int wm0 = wv * 48;
  short8 afr[2][3];
  #pragma unroll
  for (int ks = 0; ks < 2; ++ks)
    #pragma unroll
    for (int mf = 0; mf < 3; ++mf)
      afr[ks][mf] = *(const short8*)(W1 + (size_t)(wm0 + mf * 16 + l15) * CC
                                     + (ks << 5) + (l4 << 3));

  if (tid < OO) {
    sWb[tid] = Wb[tid];
  } else if (tid >= 192) {
    const int c = tid - 192;
    const float s = bg[c] * rsqrtf(bv[c] + EPS);
    sS[c] = s;
    sOff[c] = bb[c] - bm[c] * s;
  }

  // ---- stage sH: [f 0..111][ci 64], f>=104 zeroed, XOR-swizzled ----
  for (int it = tid; it < 14 * 64; it += 256) {
    const int ci = it & 63, fc = it >> 6;   // fc 0..13
    const int flb = fc << 3;
    const int fg = f0 + flb;
    unsigned short e[8];
    if (flb >= 104) {
      #pragma unroll
      for (int j = 0; j < 8; ++j) e[j] = 0;
    } else if (F32IN) {
      const float* hb = (const float*)hin + ((size_t)n * CC + ci) * TV;
      if (fg + 8 <= TV) {
        const float4 v0 = *(const float4*)(hb + fg);
        const float4 v1 = *(const float4*)(hb + fg + 4);
        e[0] = (unsigned short)f2bf(v0.x); e[1] = (unsigned short)f2bf(v0.y);
        e[2] = (unsigned short)f2bf(v0.z); e[3] = (unsigned short)f2bf(v0.w);
        e[4] = (unsigned short)f2bf(v1.x); e[5] = (unsigned short)f2bf(v1.y);
        e[6] = (unsigned short)f2bf(v1.z); e[7] = (unsigned short)f2bf(v1.w);
      } else {
        #pragma unroll
        for (int j = 0; j < 8; ++j)
          e[j] = (fg + j < TV) ? (unsigned short)f2bf(hb[fg + j])
                               : (unsigned short)0;
      }
    } else {
      const unsigned short* hb = (const unsigned short*)hin
                                 + ((size_t)n * CC + ci) * TV;
      if (fg + 8 <= TV) {
        const uint2 v0 = *(const uint2*)(hb + fg);
        const uint2 v1 = *(const uint2*)(hb + fg + 4);
        e[0] = (unsigned short)(v0.x & 0xffffu); e[1] = (unsigned short)(v0.x >> 16);
        e[2] = (unsigned short)(v0.y & 0xffffu); e[3] = (unsigned short)(v0.y >> 16);
        e[4] = (unsigned short)(v1.x & 0xffffu); e[5] = (unsigned short)(v1.x >> 16);
        e[6] = (unsigned short)(v1.y & 0xffffu); e[7] = (unsigned short)(v1.y >> 16);
      } else {
        #pragma unroll
        for (int j = 0; j < 8; ++j)
          e[j] = (fg + j < TV) ? hb[fg + j] : (unsigned short)0;
      }
    }
    const int cg8 = ci >> 3, cl = ci & 7;
    #pragma unroll
    for (int j = 0; j < 8; ++j)     // flb%8==0 -> ((flb+j)&7)==j
      sH[((flb + j) << 6) + ((cg8 ^ j) << 3) + cl] = e[j];
  }
  __syncthreads();

  // ---- GEMM1: 48 o x 112 f per wave ----
  f32x4 acc[3][7] = {};
  #pragma unroll
  for (int ks = 0; ks < 2; ++ks) {
    short8 bfr[7];
    const int cg = (ks << 2) + l4;
    #pragma unroll
    for (int nf = 0; nf < 7; ++nf) {
      const int fl = nf * 16 + l15;
      bfr[nf] = *(const short8*)&sH[(fl << 6) + ((cg ^ (fl & 7)) << 3)];
    }
    #pragma unroll
    for (int mf = 0; mf < 3; ++mf)
      #pragma unroll
      for (int nf = 0; nf < 7; ++nf)
        acc[mf][nf] = __builtin_amdgcn_mfma_f32_16x16x32_bf16(
            afr[ks][mf], bfr[nf], acc[mf][nf], 0, 0, 0);
  }
  // epilogue -> sY (all f<112 written; cols 112..119 never read)
  #pragma unroll
  for (int mf = 0; mf < 3; ++mf)
    #pragma unroll
    for (int r = 0; r < 4; ++r) {
      const int o = wm0 + mf * 16 + (l4 << 2) + r;
      const float bias = sWb[o];
      unsigned short* yr = &sY[o * 120 + l15];
      #pragma unroll
      for (int nf = 0; nf < 7; ++nf)
        yr[nf * 16] = (unsigned short)f2bf(acc[mf][nf][r] + bias);
    }
  __syncthreads();

  // ---- GEMM2: wave = t_loc; M=64 c, N=2x16 w, K=3x32 (k,v) ----
  const int t = t0 + wv;
  if (t < TT_) {
    f32x4 a2[4][2] = {};
    const int cuoff = wv * 13 + (l4 << 2);   // uint offset in sY row
    #pragma unroll
    for (int k = 0; k < KK; ++k)
      #pragma unroll
      for (int mf = 0; mf < 4; ++mf) {
        const unsigned int* rb =
            (const unsigned int*)&sY[(k * 64 + mf * 16 + l15) * 120];
        union { unsigned int u[4]; short8 s; } av;
        av.u[0] = rb[cuoff];     av.u[1] = rb[cuoff + 1];
        av.u[2] = rb[cuoff + 2]; av.u[3] = rb[cuoff + 3];
        #pragma unroll
        for (int nf = 0; nf < 2; ++nf)
          a2[mf][nf] = __builtin_amdgcn_mfma_f32_16x16x32_bf16(
              av.s, amf[k][nf], a2[mf][nf], 0, 0, 0);
      }
    #pragma unroll
    for (int mf = 0; mf < 4; ++mf)
      #pragma unroll
      for (int r = 0; r < 4; ++r) {
        const int c = mf * 16 + (l4 << 2) + r;
        const float s = sS[c], off = sOff[c];
        unsigned short* op = hout + ((size_t)n * CC + c) * TV + t * VV;
        op[l15] = (unsigned short)f2bf(fmaxf(fmaf(a2[mf][0][r], s, off), 0.f));
        if (l15 < 10)
          op[16 + l15] =
              (unsigned short)f2bf(fmaxf(fmaf(a2[mf][1][r], s, off), 0.f));
      }
  }
}

// ---------------------------------------------------------------------------
// K2 (MFMA): temporal conv (validated R4) — output dtype templated:
// bf16 for layers 0/1 (feeds fused kernel; same value f2bf produced anyway),
// f32 for layer 2 (head path unchanged).
// ---------------------------------------------------------------------------
template<int F32OUT>
__global__ __launch_bounds__(256) void k_tconv_mfma(
    const unsigned short* __restrict__ xin,  // [16][64][TV] bf16
    const unsigned short* __restrict__ W2,   // [64][576] bf16
    const float* __restrict__ wb, const float* __restrict__ bg,
    const float* __restrict__ bb, const float* __restrict__ bm,
    const float* __restrict__ bv, void* __restrict__ xout)
{
  const int NFT = (TV + 255) >> 8;  // 65
  const int n = blockIdx.x / NFT, ft = blockIdx.x % NFT;
  const int f0 = ft << 8;
  const int tid = threadIdx.x;
  const int w = tid >> 6, lane = tid & 63;
  const int l15 = lane & 15, l4 = lane >> 4;
  __shared__ unsigned short sIn[464 * 64];  // 59392 B

  const unsigned short* xb = xin + (size_t)n * CC * TV;
  for (int it = tid; it < 58 * 64; it += 256) {
    const int ci = it & 63, fc = it >> 6;   // fc 0..57
    const int flb = fc << 3;
    const int fg = f0 - 104 + flb;
    unsigned short e[8];
    if (fg >= 0 && fg + 8 <= TV) {
      const uint2 v0 = *(const uint2*)(xb + (size_t)ci * TV + fg);
      const uint2 v1 = *(const uint2*)(xb + (size_t)ci * TV + fg + 4);
      e[0] = (unsigned short)(v0.x & 0xffffu); e[1] = (unsigned short)(v0.x >> 16);
      e[2] = (unsigned short)(v0.y & 0xffffu); e[3] = (unsigned short)(v0.y >> 16);
      e[4] = (unsigned short)(v1.x & 0xffffu); e[5] = (unsigned short)(v1.x >> 16);
      e[6] = (unsigned short)(v1.y & 0xffffu); e[7] = (unsigned short)(v1.y >> 16);
    } else {
      #pragma unroll
      for (int j = 0; j < 8; ++j) {
        const int f = fg + j;
        e[j] = (f >= 0 && f < TV) ? xb[(size_t)ci * TV + f] : (unsigned short)0;
      }
    }
    const int cg8 = ci >> 3, cl = ci & 7;
    #pragma unroll
    for (int j = 0; j < 8; ++j) {
      sIn[((flb + j) << 6) + ((cg8 ^ j) << 3) + cl] = e[j];
    }
  }
  __syncthreads();

  const int w64 = w << 6;
  f32x4 acc[4][4] = {};
  short8 aCur[4], aNxt[4];
  {
    const int koff = (l4 << 3);
    #pragma unroll
    for (int mt = 0; mt < 4; ++mt)
      aCur[mt] = *(const short8*)(W2 + (size_t)(mt * 16 + l15) * 576 + koff);
  }
  for (int s = 0; s < 18; ++s) {
    if (s < 17) {
      const int s1 = s + 1;
      const int koff = ((s1 >> 1) << 6) + ((s1 & 1) << 5) + (l4 << 3);
      #pragma unroll
      for (int mt = 0; mt < 4; ++mt)
        aNxt[mt] = *(const short8*)(W2 + (size_t)(mt * 16 + l15) * 576 + koff);
    }
    const int dt = s >> 1;
    const int cg = ((s & 1) << 2) + l4;
    const int flb = w64 + l15 + (dt - 4) * 26 + 104;
    short8 bfrag[4];
    #pragma unroll
    for (int nt = 0; nt < 4; ++nt) {
      const int fl = flb + (nt << 4);
      bfrag[nt] = *(const short8*)&sIn[(fl << 6) + ((cg ^ (fl & 7)) << 3)];
    }
    #pragma unroll
    for (int mt = 0; mt < 4; ++mt)
      #pragma unroll
      for (int nt = 0; nt < 4; ++nt)
        acc[mt][nt] = __builtin_amdgcn_mfma_f32_16x16x32_bf16(
            aCur[mt], bfrag[nt], acc[mt][nt], 0, 0, 0);
    if (s < 17) {
      #pragma unroll
      for (int mt = 0; mt < 4; ++mt) aCur[mt] = aNxt[mt];
    }
  }

  #pragma unroll
  for (int mt = 0; mt < 4; ++mt) {
    #pragma unroll
    for (int r = 0; r < 4; ++r) {
      const int c = mt * 16 + (l4 << 2) + r;
      const float sc = bg[c] * rsqrtf(bv[c] + EPS);
      const float off = fmaf(wb[c] - bm[c], sc, bb[c]);
      #pragma unroll
      for (int nt = 0; nt < 4; ++nt) {
        const int f = f0 + w64 + (nt << 4) + l15;
        if (f < TV) {
          const float val = fmaxf(fmaf(acc[mt][nt][r], sc, off), 0.f);
          if (F32OUT)
            ((float*)xout)[((size_t)n * CC + c) * TV + f] = val;
          else
            ((unsigned short*)xout)[((size_t)n * CC + c) * TV + f] =
                (unsigned short)f2bf(val);
        }
      }
    }
  }
}

// ---------------------------------------------------------------------------
// K3a: pooled / per-v T-mean  (unchanged, reads f32 bufB)
// ---------------------------------------------------------------------------
__global__ __launch_bounds__(256) void k_pool(
    const float* __restrict__ h, float* __restrict__ pooled,
    float* __restrict__ hmeanv)
{
  const int tid = threadIdx.x;
  const int bid = blockIdx.x;
  const float* row = h + (size_t)bid * TV;
  __shared__ float part[9 * VV];
  if (tid < 9 * VV) {
    const int tt = tid / VV, v = tid - tt * VV;
    float s = 0.f;
    for (int t = tt; t < TT_; t += 9) s += row[t * VV + v];
    part[tid] = s;
  }
  __syncthreads();
  if (tid < VV) {
    float tot = 0.f;
    #pragma unroll
    for (int j = 0; j < 9; ++j) tot += part[j * VV + tid];
    hmeanv[(size_t)bid * VV + tid] = tot / (float)TT_;
    part[tid] = tot;
  }
  __syncthreads();
  if (tid == 0) {
    float tot = 0.f;
    for (int v = 0; v < VV; ++v) tot += part[v];
    pooled[bid] = tot / (float)TV;
  }
}

// ---------------------------------------------------------------------------
// K3b: per-n head  (unchanged)
// ---------------------------------------------------------------------------
__global__ __launch_bounds__(256) void k_head_edge(
    const float* __restrict__ pooled, const float* __restrict__ hmeanv,
    const float* __restrict__ fcw, const float* __restrict__ fcb,
    const float* __restrict__ ag, const float* __restrict__ ab,
    const float* __restrict__ am, const float* __restrict__ av,
    const float* __restrict__ attw, const float* __restrict__ edgew,
    const float* __restrict__ eg, const float* __restrict__ eb,
    const float* __restrict__ em, const float* __restrict__ ev,
    float* __restrict__ dout)
{
  const int tid = threadIdx.x;
  const int n = blockIdx.x;
  __shared__ float sbnm[CC * VV];
  __shared__ float sxam[NCLS * VV];
  __shared__ float spool[CC];
  for (int i = tid; i < CC * VV; i += 256) {
    const int c = i / VV;
    const float s = ag[c] * rsqrtf(av[c] + EPS);
    const float off = ab[c] - am[c] * s;
    sbnm[i] = fmaf(hmeanv[(size_t)(n * CC) * VV + i], s, off);
  }
  if (tid < CC) spool[tid] = pooled[n * CC + tid];
  __syncthreads();
  for (int i = tid; i < NCLS * VV; i += 256) {
    const int o = i / VV, v = i - o * VV;
    float a = 0.f;
    for (int c = 0; c < CC; ++c) a = fmaf(attw[o * CC + c], sbnm[c * VV + v], a);
    sxam[i] = a;
  }
  if (tid < NCLS) {
    float a = fcb[tid];
    for (int c = 0; c < CC; ++c) a = fmaf(spool[c], fcw[tid * CC + c], a);
    dout[n * NCLS + tid] = a;
  }
  __syncthreads();
  for (int i = tid; i < NAE * VV * VV; i += 256) {
    const int j = i / VV, v = i - j * VV;
    float a = 0.f;
    for (int o = 0; o < NCLS; ++o) a = fmaf(edgew[j * NCLS + o], sxam[o * VV + v], a);
    const float s = eg[j] * rsqrtf(ev[j] + EPS);
    const float val = tanhf(fmaf(a - em[j], s, eb[j]));
    dout[NN * NCLS + (size_t)NN * TV + (size_t)n * NAE * VV * VV + i] = fmaxf(val, 0.f);
  }
}

// ---------------------------------------------------------------------------
// K3c: node attention  (unchanged)
// ---------------------------------------------------------------------------
__global__ __launch_bounds__(256) void k_node(
    const float* __restrict__ h,
    const float* __restrict__ ag, const float* __restrict__ ab,
    const float* __restrict__ am, const float* __restrict__ av,
    const float* __restrict__ attw, const float* __restrict__ nodew,
    const float* __restrict__ ng, const float* __restrict__ nb,
    const float* __restrict__ nm, const float* __restrict__ nv,
    float* __restrict__ dout)
{
  const int tid = threadIdx.x;
  __shared__ float ac[CC];
  __shared__ float tmp[CC];
  if (tid < CC) {
    float nc = 0.f;
    for (int o = 0; o < NCLS; ++o) nc = fmaf(nodew[o], attw[o * CC + tid], nc);
    const float s = ag[tid] * rsqrtf(av[tid] + EPS);
    const float off = ab[tid] - am[tid] * s;
    ac[tid] = nc * s;
    tmp[tid] = nc * off;
  }
  __syncthreads();
  if (tid == 0) {
    float b = 0.f;
    for (int c = 0; c < CC; ++c) b += tmp[c];
    tmp[0] = b;
  }
  __syncthreads();
  const float b0 = tmp[0];
  const size_t i = (size_t)blockIdx.x * 256 + tid;
  if (i < (size_t)NN * TV) {
    const int n = (int)(i / TV), f = (int)(i - (size_t)n * TV);
    const float* hb = h + (size_t)n * CC * TV + f;
    float xsum = b0;
    #pragma unroll 8
    for (int c = 0; c < CC; ++c) xsum = fmaf(hb[(size_t)c * TV], ac[c], xsum);
    const float s = ng[0] * rsqrtf(nv[0] + EPS);
    const float y = fmaf(xsum - nm[0], s, nb[0]);
    dout[NN * NCLS + i] = 1.f / (1.f + expf(-y));
  }
}

// ---------------------------------------------------------------------------
extern "C" void kernel_launch(void* const* d_in, const int* in_sizes, int n_in,
                              void* d_out, int out_size, void* d_ws, size_t ws_size,
                              hipStream_t stream) {
  const float* x        = (const float*)d_in[0];
  const float* A        = (const float*)d_in[1];
  const float* sgc_w    = (const float*)d_in[2];
  const float* sgc_b    = (const float*)d_in[3];
  const float* M        = (const float*)d_in[4];
  const float* bnA_g    = (const float*)d_in[5];
  const float* bnA_b    = (const float*)d_in[6];
  const float* bnA_m    = (const float*)d_in[7];
  const float* bnA_v    = (const float*)d_in[8];
  const float* tconv_w  = (const float*)d_in[9];
  const float* tconv_b  = (const float*)d_in[10];
  const float* bnB_g    = (const float*)d_in[11];
  const float* bnB_b    = (const float*)d_in[12];
  const float* bnB_m    = (const float*)d_in[13];
  const float* bnB_v    = (const float*)d_in[14];
  const float* fc_w     = (const float*)d_in[15];
  const float* fc_b     = (const float*)d_in[16];
  const float* attbn_g  = (const float*)d_in[17];
  const float* attbn_b  = (const float*)d_in[18];
  const float* attbn_m  = (const float*)d_in[19];
  const float* attbn_v  = (const float*)d_in[20];
  // d_in[21..34]: transformer branch params — dead code in the reference.
  const float* attconv_w  = (const float*)d_in[35];
  const float* nodeconv_w = (const float*)d_in[36];
  const float* nodebn_g   = (const float*)d_in[37];
  const float* nodebn_b   = (const float*)d_in[38];
  const float* nodebn_m   = (const float*)d_in[39];
  const float* nodebn_v   = (const float*)d_in[40];
  const float* edgeconv_w = (const float*)d_in[41];
  const float* edgebn_g   = (const float*)d_in[42];
  const float* edgebn_b   = (const float*)d_in[43];
  const float* edgebn_m   = (const float*)d_in[44];
  const float* edgebn_v   = (const float*)d_in[45];

  // workspace layout
  float* pooled = (float*)d_ws;                              // 1024 f32
  float* hmeanv = pooled + NN * CC;                          // 26624 f32
  unsigned short* W1all = (unsigned short*)(hmeanv + (size_t)NN * CC * VV);
  unsigned short* W2all = W1all + W1_ELEMS;
  unsigned short* AMall = W2all + W2_ELEMS;
  unsigned short* bufA  = AMall + AM_ELEMS;                  // bf16 hA
  unsigned short* bufBh = bufA + (size_t)NN * CC * TV;       // bf16 h (L0/L1)
  float* bufB = (float*)(bufBh + (size_t)NN * CC * TV);      // f32 h (L2)
  float* out = (float*)d_out;

  const int PREP_TOT = W1_ELEMS + W2_ELEMS + AM_ELEMS;
  k_prep_all<<<(PREP_TOT + 255) / 256, 256, 0, stream>>>(
      sgc_w, tconv_w, A, M, W1all, W2all, AMall);

  const int GF = NN * 159;           // fused grid
  const int NFC = (TV + 255) >> 8;   // 65
  for (int i = 0; i < 3; ++i) {
    const unsigned short* W1i = W1all + (size_t)i * OO * CC;
    const unsigned short* W2i = W2all + (size_t)i * CC * 576;
    const unsigned short* AMi = AMall + (size_t)i * KK * 1024;
    if (i == 0)
      k_fused_sgc<1><<<GF, 256, 0, stream>>>(
          x, W1i, sgc_b, AMi,
          bnA_g, bnA_b, bnA_m, bnA_v, bufA);
    else
      k_fused_sgc<0><<<GF, 256, 0, stream>>>(
          bufBh, W1i, sgc_b + i * OO, AMi,
          bnA_g + i * CC, bnA_b + i * CC, bnA_m + i * CC, bnA_v + i * CC,
          bufA);
    if (i < 2)
      k_tconv_mfma<0><<<NN * NFC, 256, 0, stream>>>(
          bufA, W2i, tconv_b + i * CC,
          bnB_g + i * CC, bnB_b + i * CC, bnB_m + i * CC, bnB_v + i * CC,
          (void*)bufBh);
    else
      k_tconv_mfma<1><<<NN * NFC, 256, 0, stream>>>(
          bufA, W2i, tconv_b + i * CC,
          bnB_g + i * CC, bnB_b + i * CC, bnB_m + i * CC, bnB_v + i * CC,
          (void*)bufB);
  }
  k_pool<<<NN * CC, 256, 0, stream>>>(bufB, pooled, hmeanv);
  k_head_edge<<<NN, 256, 0, stream>>>(pooled, hmeanv, fc_w, fc_b,
      attbn_g, attbn_b, attbn_m, attbn_v, attconv_w, edgeconv_w,
      edgebn_g, edgebn_b, edgebn_m, edgebn_v, out);
  k_node<<<((size_t)NN * TV + 255) / 256, 256, 0, stream>>>(
      bufB, attbn_g, attbn_b, attbn_m, attbn_v, attconv_w, nodeconv_w,
      nodebn_g, nodebn_b, nodebn_m, nodebn_v, out);
}

// Round 9
// 597.695 us; speedup vs baseline: 4.5822x; 1.0590x over previous
//
#include <hip/hip_runtime.h>
#include <hip/hip_bf16.h>
#include <math.h>

#define NN 16
#define CC 64
#define TT_ 634
#define VV 26
#define TV 16484      // TT_*VV
#define KK 3
#define OO 192        // KK*CC
#define TKK 9
#define NCLS 60
#define NAE 4
#define EPS 1e-5f

typedef __attribute__((ext_vector_type(8))) short short8;
typedef __attribute__((ext_vector_type(4))) float f32x4;

static __device__ __forceinline__ float bf2f(unsigned int u) {
  union { unsigned int i; float f; } v; v.i = u << 16; return v.f;
}
static __device__ __forceinline__ unsigned int f2bf(float x) {
  union { float f; unsigned int i; } v; v.f = x;
  unsigned int r = v.i + 0x7fffu + ((v.i >> 16) & 1u);
  return r >> 16;
}

#define W1_ELEMS (3 * OO * CC)     // 36864
#define W2_ELEMS (3 * CC * 576)    // 110592
#define AM_ELEMS (3 * KK * 1024)   // 9216

// ---------------------------------------------------------------------------
// Prep (once): all 3 layers' weights -> bf16.  (validated R6)
// ---------------------------------------------------------------------------
__global__ __launch_bounds__(256) void k_prep_all(
    const float* __restrict__ sgc_w, const float* __restrict__ tconv_w,
    const float* __restrict__ Ap, const float* __restrict__ Mp,
    unsigned short* __restrict__ W1all, unsigned short* __restrict__ W2all,
    unsigned short* __restrict__ AMall)
{
  int j = blockIdx.x * 256 + threadIdx.x;
  if (j < W1_ELEMS) { W1all[j] = (unsigned short)f2bf(sgc_w[j]); return; }
  j -= W1_ELEMS;
  if (j < W2_ELEMS) {
    const int i = j / (CC * 576), r = j % (CC * 576);
    const int c = r / 576, q = r % 576, dt = q >> 6, ci = q & 63;
    W2all[j] = (unsigned short)f2bf(
        tconv_w[(size_t)i * CC * CC * TKK + c * 576 + ci * 9 + dt]);
    return;
  }
  j -= W2_ELEMS;
  if (j < AM_ELEMS) {
    const int i = j / (KK * 1024), r = j % (KK * 1024);
    const int k = r >> 10, rr = r & 1023;
    const int w = rr >> 5, v = rr & 31;
    float val = 0.f;
    if (w < VV && v < VV)
      val = Ap[(k * VV + v) * VV + w] *
            Mp[((size_t)i * KK + k) * VV * VV + v * VV + w];
    AMall[j] = (unsigned short)f2bf(val);
  }
}

// ---------------------------------------------------------------------------
// Fused SGC: pw-conv (GEMM1) + graph contraction (GEMM2) + bnA + relu.
// R8 change: sH overlaid into sY (sH dead once GEMM1 accs are in registers;
// extra barrier between last sH read and first sY write).  LDS 61.7->47.4 KB
// -> 3 blocks/CU.
// ---------------------------------------------------------------------------
template<int F32IN>
__global__ __launch_bounds__(256) void k_fused_sgc(
    const void* __restrict__ hin,           // [16][64][TV] f32 or bf16
    const unsigned short* __restrict__ W1,  // [192][64] bf16 layer slice
    const float* __restrict__ Wb,           // [192]
    const unsigned short* __restrict__ AMk, // [KK][32][32] bf16 layer slice
    const float* __restrict__ bg, const float* __restrict__ bb,
    const float* __restrict__ bm, const float* __restrict__ bv,
    unsigned short* __restrict__ hout)      // [16][64][TV] bf16
{
  const int NTT = 159;
  const int n = blockIdx.x / NTT, tt = blockIdx.x % NTT;
  const int t0 = tt << 2;
  const int f0 = t0 * VV;
  const int tid = threadIdx.x;
  const int wv = tid >> 6, lane = tid & 63;
  const int l15 = lane & 15, l4 = lane >> 4;

  __shared__ unsigned short sY[192 * 120];  // 46080 B; sH aliased on top
  __shared__ float sWb[OO];
  __shared__ float sS[CC], sOff[CC];
  unsigned short* sH = sY;                  // [f 112][ci 64] during GEMM1

  // GEMM2 B-frags (AM table, 6 KB L2) — hoisted
  short8 amf[KK][2];
  #pragma unroll
  for (int k = 0; k < KK; ++k)
    #pragma unroll
    for (int nf = 0; nf < 2; ++nf)
      amf[k][nf] = *(const short8*)(AMk + (k << 10) + ((nf * 16 + l15) << 5)
                                    + (l4 << 3));

  // GEMM1 A-frags (W1, 24 KB L2)
  const int wm0 = wv * 48;
  short8 afr[2][3];
  #pragma unroll
  for (int ks = 0; ks < 2; ++ks)
    #pragma unroll
    for (int mf = 0; mf < 3; ++mf)
      afr[ks][mf] = *(const short8*)(W1 + (size_t)(wm0 + mf * 16 + l15) * CC
                                     + (ks << 5) + (l4 << 3));

  if (tid < OO) {
    sWb[tid] = Wb[tid];
  } else if (tid >= 192) {
    const int c = tid - 192;
    const float s = bg[c] * rsqrtf(bv[c] + EPS);
    sS[c] = s;
    sOff[c] = bb[c] - bm[c] * s;
  }

  // ---- stage sH: [f 0..111][ci 64], f>=104 zeroed, XOR-swizzled ----
  for (int it = tid; it < 14 * 64; it += 256) {
    const int ci = it & 63, fc = it >> 6;   // fc 0..13
    const int flb = fc << 3;
    const int fg = f0 + flb;
    unsigned short e[8];
    if (flb >= 104) {
      #pragma unroll
      for (int j = 0; j < 8; ++j) e[j] = 0;
    } else if (F32IN) {
      const float* hb = (const float*)hin + ((size_t)n * CC + ci) * TV;
      if (fg + 8 <= TV) {
        const float4 v0 = *(const float4*)(hb + fg);
        const float4 v1 = *(const float4*)(hb + fg + 4);
        e[0] = (unsigned short)f2bf(v0.x); e[1] = (unsigned short)f2bf(v0.y);
        e[2] = (unsigned short)f2bf(v0.z); e[3] = (unsigned short)f2bf(v0.w);
        e[4] = (unsigned short)f2bf(v1.x); e[5] = (unsigned short)f2bf(v1.y);
        e[6] = (unsigned short)f2bf(v1.z); e[7] = (unsigned short)f2bf(v1.w);
      } else {
        #pragma unroll
        for (int j = 0; j < 8; ++j)
          e[j] = (fg + j < TV) ? (unsigned short)f2bf(hb[fg + j])
                               : (unsigned short)0;
      }
    } else {
      const unsigned short* hb = (const unsigned short*)hin
                                 + ((size_t)n * CC + ci) * TV;
      if (fg + 8 <= TV) {
        const uint2 v0 = *(const uint2*)(hb + fg);
        const uint2 v1 = *(const uint2*)(hb + fg + 4);
        e[0] = (unsigned short)(v0.x & 0xffffu); e[1] = (unsigned short)(v0.x >> 16);
        e[2] = (unsigned short)(v0.y & 0xffffu); e[3] = (unsigned short)(v0.y >> 16);
        e[4] = (unsigned short)(v1.x & 0xffffu); e[5] = (unsigned short)(v1.x >> 16);
        e[6] = (unsigned short)(v1.y & 0xffffu); e[7] = (unsigned short)(v1.y >> 16);
      } else {
        #pragma unroll
        for (int j = 0; j < 8; ++j)
          e[j] = (fg + j < TV) ? hb[fg + j] : (unsigned short)0;
      }
    }
    const int cg8 = ci >> 3, cl = ci & 7;
    #pragma unroll
    for (int j = 0; j < 8; ++j)     // flb%8==0 -> ((flb+j)&7)==j
      sH[((flb + j) << 6) + ((cg8 ^ j) << 3) + cl] = e[j];
  }
  __syncthreads();

  // ---- GEMM1: 48 o x 112 f per wave (reads sH; acc stays in regs) ----
  f32x4 acc[3][7] = {};
  #pragma unroll
  for (int ks = 0; ks < 2; ++ks) {
    short8 bfr[7];
    const int cg = (ks << 2) + l4;
    #pragma unroll
    for (int nf = 0; nf < 7; ++nf) {
      const int fl = nf * 16 + l15;
      bfr[nf] = *(const short8*)&sH[(fl << 6) + ((cg ^ (fl & 7)) << 3)];
    }
    #pragma unroll
    for (int mf = 0; mf < 3; ++mf)
      #pragma unroll
      for (int nf = 0; nf < 7; ++nf)
        acc[mf][nf] = __builtin_amdgcn_mfma_f32_16x16x32_bf16(
            afr[ks][mf], bfr[nf], acc[mf][nf], 0, 0, 0);
  }
  __syncthreads();   // sH reads done -> safe to overwrite with sY

  // epilogue -> sY (all f<112 written; cols 112..119 never read)
  #pragma unroll
  for (int mf = 0; mf < 3; ++mf)
    #pragma unroll
    for (int r = 0; r < 4; ++r) {
      const int o = wm0 + mf * 16 + (l4 << 2) + r;
      const float bias = sWb[o];
      unsigned short* yr = &sY[o * 120 + l15];
      #pragma unroll
      for (int nf = 0; nf < 7; ++nf)
        yr[nf * 16] = (unsigned short)f2bf(acc[mf][nf][r] + bias);
    }
  __syncthreads();

  // ---- GEMM2: wave = t_loc; M=64 c, N=2x16 w, K=3x32 (k,v) ----
  const int t = t0 + wv;
  if (t < TT_) {
    f32x4 a2[4][2] = {};
    const int cuoff = wv * 13 + (l4 << 2);   // uint offset in sY row
    #pragma unroll
    for (int k = 0; k < KK; ++k)
      #pragma unroll
      for (int mf = 0; mf < 4; ++mf) {
        const unsigned int* rb =
            (const unsigned int*)&sY[(k * 64 + mf * 16 + l15) * 120];
        union { unsigned int u[4]; short8 s; } av;
        av.u[0] = rb[cuoff];     av.u[1] = rb[cuoff + 1];
        av.u[2] = rb[cuoff + 2]; av.u[3] = rb[cuoff + 3];
        #pragma unroll
        for (int nf = 0; nf < 2; ++nf)
          a2[mf][nf] = __builtin_amdgcn_mfma_f32_16x16x32_bf16(
              av.s, amf[k][nf], a2[mf][nf], 0, 0, 0);
      }
    #pragma unroll
    for (int mf = 0; mf < 4; ++mf)
      #pragma unroll
      for (int r = 0; r < 4; ++r) {
        const int c = mf * 16 + (l4 << 2) + r;
        const float s = sS[c], off = sOff[c];
        unsigned short* op = hout + ((size_t)n * CC + c) * TV + t * VV;
        op[l15] = (unsigned short)f2bf(fmaxf(fmaf(a2[mf][0][r], s, off), 0.f));
        if (l15 < 10)
          op[16 + l15] =
              (unsigned short)f2bf(fmaxf(fmaf(a2[mf][1][r], s, off), 0.f));
      }
  }
}

// ---------------------------------------------------------------------------
// K2 (MFMA): temporal conv.  R8 changes:
//  (a) ci-split staging (2 chunks of 32) -> LDS 29696 B -> 5 blocks/CU;
//      swizzle g = cg ^ ((f>>1)&3) over 4 granules/row (2-way = free).
//  (b) swapped MFMA operands: C row=f, col=c -> each lane stores 4
//      consecutive f (8B bf16 / 16B f32) instead of 4 scalar stores.
// ---------------------------------------------------------------------------
template<int F32OUT>
__global__ __launch_bounds__(256) void k_tconv_mfma(
    const unsigned short* __restrict__ xin,  // [16][64][TV] bf16
    const unsigned short* __restrict__ W2,   // [64][576] bf16
    const float* __restrict__ wb, const float* __restrict__ bg,
    const float* __restrict__ bb, const float* __restrict__ bm,
    const float* __restrict__ bv, void* __restrict__ xout)
{
  const int NFT = (TV + 255) >> 8;  // 65
  const int n = blockIdx.x / NFT, ft = blockIdx.x % NFT;
  const int f0 = ft << 8;
  const int tid = threadIdx.x;
  const int w = tid >> 6, lane = tid & 63;
  const int l15 = lane & 15, l4 = lane >> 4;
  __shared__ unsigned short sIn[464 * 32];  // 29696 B, [f][ci32] swizzled

  const unsigned short* xb = xin + (size_t)n * CC * TV;
  const int w64 = w << 6;
  f32x4 acc[4][4] = {};   // [c-tile][f-tile], row=f col=c after swap

  for (int cc = 0; cc < 2; ++cc) {
    if (cc) __syncthreads();
    // ---- stage 32-ci chunk ----
    for (int it = tid; it < 58 * 32; it += 256) {
      const int ci = it & 31, fc = it >> 5;   // fc 0..57
      const int flb = fc << 3;
      const int fg = f0 - 104 + flb;
      const int cig = (cc << 5) + ci;
      unsigned short e[8];
      if (fg >= 0 && fg + 8 <= TV) {
        const uint2 v0 = *(const uint2*)(xb + (size_t)cig * TV + fg);
        const uint2 v1 = *(const uint2*)(xb + (size_t)cig * TV + fg + 4);
        e[0] = (unsigned short)(v0.x & 0xffffu); e[1] = (unsigned short)(v0.x >> 16);
        e[2] = (unsigned short)(v0.y & 0xffffu); e[3] = (unsigned short)(v0.y >> 16);
        e[4] = (unsigned short)(v1.x & 0xffffu); e[5] = (unsigned short)(v1.x >> 16);
        e[6] = (unsigned short)(v1.y & 0xffffu); e[7] = (unsigned short)(v1.y >> 16);
      } else {
        #pragma unroll
        for (int j = 0; j < 8; ++j) {
          const int f = fg + j;
          e[j] = (f >= 0 && f < TV) ? xb[(size_t)cig * TV + f] : (unsigned short)0;
        }
      }
      const int cg8 = ci >> 3, cl = ci & 7;
      #pragma unroll
      for (int j = 0; j < 8; ++j) {
        const int fl = flb + j;
        sIn[(fl << 5) + ((cg8 ^ ((fl >> 1) & 3)) << 3) + cl] = e[j];
      }
    }
    __syncthreads();

    // ---- 9 dt k-steps (K=32 ci each) ----
    short8 wCur[4], wNxt[4];
    {
      const int koff = (cc << 5) + (l4 << 3);   // dt = 0
      #pragma unroll
      for (int mt = 0; mt < 4; ++mt)
        wCur[mt] = *(const short8*)(W2 + (size_t)(mt * 16 + l15) * 576 + koff);
    }
    for (int dt = 0; dt < TKK; ++dt) {
      if (dt < 8) {
        const int koff = ((dt + 1) << 6) + (cc << 5) + (l4 << 3);
        #pragma unroll
        for (int mt = 0; mt < 4; ++mt)
          wNxt[mt] = *(const short8*)(W2 + (size_t)(mt * 16 + l15) * 576 + koff);
      }
      const int flb = w64 + l15 + (dt - 4) * 26 + 104;
      short8 ifr[4];
      #pragma unroll
      for (int nt = 0; nt < 4; ++nt) {
        const int fl = flb + (nt << 4);
        ifr[nt] = *(const short8*)&sIn[(fl << 5)
                                       + ((l4 ^ ((fl >> 1) & 3)) << 3)];
      }
      #pragma unroll
      for (int mt = 0; mt < 4; ++mt)
        #pragma unroll
        for (int nt = 0; nt < 4; ++nt)
          acc[mt][nt] = __builtin_amdgcn_mfma_f32_16x16x32_bf16(
              ifr[nt], wCur[mt], acc[mt][nt], 0, 0, 0);
      if (dt < 8) {
        #pragma unroll
        for (int mt = 0; mt < 4; ++mt) wCur[mt] = wNxt[mt];
      }
    }
  }

  // ---- epilogue: row=f=(l4<<2)+r, col=c=l15; 4 consecutive f per lane ----
  #pragma unroll
  for (int mt = 0; mt < 4; ++mt) {
    const int c = mt * 16 + l15;
    const float sc = bg[c] * rsqrtf(bv[c] + EPS);
    const float off = fmaf(wb[c] - bm[c], sc, bb[c]);
    #pragma unroll
    for (int nt = 0; nt < 4; ++nt) {
      const int fbase = f0 + w64 + (nt << 4) + (l4 << 2);
      if (fbase < TV) {   // TV%4==0 -> quad fully in or out
        float v0 = fmaxf(fmaf(acc[mt][nt][0], sc, off), 0.f);
        float v1 = fmaxf(fmaf(acc[mt][nt][1], sc, off), 0.f);
        float v2 = fmaxf(fmaf(acc[mt][nt][2], sc, off), 0.f);
        float v3 = fmaxf(fmaf(acc[mt][nt][3], sc, off), 0.f);
        if (F32OUT) {
          float4 o4; o4.x = v0; o4.y = v1; o4.z = v2; o4.w = v3;
          *(float4*)((float*)xout + ((size_t)n * CC + c) * TV + fbase) = o4;
        } else {
          uint2 pk;
          pk.x = f2bf(v0) | (f2bf(v1) << 16);
          pk.y = f2bf(v2) | (f2bf(v3) << 16);
          *(uint2*)((unsigned short*)xout + ((size_t)n * CC + c) * TV + fbase) = pk;
        }
      }
    }
  }
}

// ---------------------------------------------------------------------------
// K3a: pooled / per-v T-mean  (unchanged, reads f32 bufB)
// ---------------------------------------------------------------------------
__global__ __launch_bounds__(256) void k_pool(
    const float* __restrict__ h, float* __restrict__ pooled,
    float* __restrict__ hmeanv)
{
  const int tid = threadIdx.x;
  const int bid = blockIdx.x;
  const float* row = h + (size_t)bid * TV;
  __shared__ float part[9 * VV];
  if (tid < 9 * VV) {
    const int tt = tid / VV, v = tid - tt * VV;
    float s = 0.f;
    for (int t = tt; t < TT_; t += 9) s += row[t * VV + v];
    part[tid] = s;
  }
  __syncthreads();
  if (tid < VV) {
    float tot = 0.f;
    #pragma unroll
    for (int j = 0; j < 9; ++j) tot += part[j * VV + tid];
    hmeanv[(size_t)bid * VV + tid] = tot / (float)TT_;
    part[tid] = tot;
  }
  __syncthreads();
  if (tid == 0) {
    float tot = 0.f;
    for (int v = 0; v < VV; ++v) tot += part[v];
    pooled[bid] = tot / (float)TV;
  }
}

// ---------------------------------------------------------------------------
// K3b: per-n head  (unchanged)
// ---------------------------------------------------------------------------
__global__ __launch_bounds__(256) void k_head_edge(
    const float* __restrict__ pooled, const float* __restrict__ hmeanv,
    const float* __restrict__ fcw, const float* __restrict__ fcb,
    const float* __restrict__ ag, const float* __restrict__ ab,
    const float* __restrict__ am, const float* __restrict__ av,
    const float* __restrict__ attw, const float* __restrict__ edgew,
    const float* __restrict__ eg, const float* __restrict__ eb,
    const float* __restrict__ em, const float* __restrict__ ev,
    float* __restrict__ dout)
{
  const int tid = threadIdx.x;
  const int n = blockIdx.x;
  __shared__ float sbnm[CC * VV];
  __shared__ float sxam[NCLS * VV];
  __shared__ float spool[CC];
  for (int i = tid; i < CC * VV; i += 256) {
    const int c = i / VV;
    const float s = ag[c] * rsqrtf(av[c] + EPS);
    const float off = ab[c] - am[c] * s;
    sbnm[i] = fmaf(hmeanv[(size_t)(n * CC) * VV + i], s, off);
  }
  if (tid < CC) spool[tid] = pooled[n * CC + tid];
  __syncthreads();
  for (int i = tid; i < NCLS * VV; i += 256) {
    const int o = i / VV, v = i - o * VV;
    float a = 0.f;
    for (int c = 0; c < CC; ++c) a = fmaf(attw[o * CC + c], sbnm[c * VV + v], a);
    sxam[i] = a;
  }
  if (tid < NCLS) {
    float a = fcb[tid];
    for (int c = 0; c < CC; ++c) a = fmaf(spool[c], fcw[tid * CC + c], a);
    dout[n * NCLS + tid] = a;
  }
  __syncthreads();
  for (int i = tid; i < NAE * VV * VV; i += 256) {
    const int j = i / VV, v = i - j * VV;
    float a = 0.f;
    for (int o = 0; o < NCLS; ++o) a = fmaf(edgew[j * NCLS + o], sxam[o * VV + v], a);
    const float s = eg[j] * rsqrtf(ev[j] + EPS);
    const float val = tanhf(fmaf(a - em[j], s, eb[j]));
    dout[NN * NCLS + (size_t)NN * TV + (size_t)n * NAE * VV * VV + i] = fmaxf(val, 0.f);
  }
}

// ---------------------------------------------------------------------------
// K3c: node attention  (unchanged)
// ---------------------------------------------------------------------------
__global__ __launch_bounds__(256) void k_node(
    const float* __restrict__ h,
    const float* __restrict__ ag, const float* __restrict__ ab,
    const float* __restrict__ am, const float* __restrict__ av,
    const float* __restrict__ attw, const float* __restrict__ nodew,
    const float* __restrict__ ng, const float* __restrict__ nb,
    const float* __restrict__ nm, const float* __restrict__ nv,
    float* __restrict__ dout)
{
  const int tid = threadIdx.x;
  __shared__ float ac[CC];
  __shared__ float tmp[CC];
  if (tid < CC) {
    float nc = 0.f;
    for (int o = 0; o < NCLS; ++o) nc = fmaf(nodew[o], attw[o * CC + tid], nc);
    const float s = ag[tid] * rsqrtf(av[tid] + EPS);
    const float off = ab[tid] - am[tid] * s;
    ac[tid] = nc * s;
    tmp[tid] = nc * off;
  }
  __syncthreads();
  if (tid == 0) {
    float b = 0.f;
    for (int c = 0; c < CC; ++c) b += tmp[c];
    tmp[0] = b;
  }
  __syncthreads();
  const float b0 = tmp[0];
  const size_t i = (size_t)blockIdx.x * 256 + tid;
  if (i < (size_t)NN * TV) {
    const int n = (int)(i / TV), f = (int)(i - (size_t)n * TV);
    const float* hb = h + (size_t)n * CC * TV + f;
    float xsum = b0;
    #pragma unroll 8
    for (int c = 0; c < CC; ++c) xsum = fmaf(hb[(size_t)c * TV], ac[c], xsum);
    const float s = ng[0] * rsqrtf(nv[0] + EPS);
    const float y = fmaf(xsum - nm[0], s, nb[0]);
    dout[NN * NCLS + i] = 1.f / (1.f + expf(-y));
  }
}

// ---------------------------------------------------------------------------
extern "C" void kernel_launch(void* const* d_in, const int* in_sizes, int n_in,
                              void* d_out, int out_size, void* d_ws, size_t ws_size,
                              hipStream_t stream) {
  const float* x        = (const float*)d_in[0];
  const float* A        = (const float*)d_in[1];
  const float* sgc_w    = (const float*)d_in[2];
  const float* sgc_b    = (const float*)d_in[3];
  const float* M        = (const float*)d_in[4];
  const float* bnA_g    = (const float*)d_in[5];
  const float* bnA_b    = (const float*)d_in[6];
  const float* bnA_m    = (const float*)d_in[7];
  const float* bnA_v    = (const float*)d_in[8];
  const float* tconv_w  = (const float*)d_in[9];
  const float* tconv_b  = (const float*)d_in[10];
  const float* bnB_g    = (const float*)d_in[11];
  const float* bnB_b    = (const float*)d_in[12];
  const float* bnB_m    = (const float*)d_in[13];
  const float* bnB_v    = (const float*)d_in[14];
  const float* fc_w     = (const float*)d_in[15];
  const float* fc_b     = (const float*)d_in[16];
  const float* attbn_g  = (const float*)d_in[17];
  const float* attbn_b  = (const float*)d_in[18];
  const float* attbn_m  = (const float*)d_in[19];
  const float* attbn_v  = (const float*)d_in[20];
  // d_in[21..34]: transformer branch params — dead code in the reference.
  const float* attconv_w  = (const float*)d_in[35];
  const float* nodeconv_w = (const float*)d_in[36];
  const float* nodebn_g   = (const float*)d_in[37];
  const float* nodebn_b   = (const float*)d_in[38];
  const float* nodebn_m   = (const float*)d_in[39];
  const float* nodebn_v   = (const float*)d_in[40];
  const float* edgeconv_w = (const float*)d_in[41];
  const float* edgebn_g   = (const float*)d_in[42];
  const float* edgebn_b   = (const float*)d_in[43];
  const float* edgebn_m   = (const float*)d_in[44];
  const float* edgebn_v   = (const float*)d_in[45];

  // workspace layout
  float* pooled = (float*)d_ws;                              // 1024 f32
  float* hmeanv = pooled + NN * CC;                          // 26624 f32
  unsigned short* W1all = (unsigned short*)(hmeanv + (size_t)NN * CC * VV);
  unsigned short* W2all = W1all + W1_ELEMS;
  unsigned short* AMall = W2all + W2_ELEMS;
  unsigned short* bufA  = AMall + AM_ELEMS;                  // bf16 hA
  unsigned short* bufBh = bufA + (size_t)NN * CC * TV;       // bf16 h (L0/L1)
  float* bufB = (float*)(bufBh + (size_t)NN * CC * TV);      // f32 h (L2)
  float* out = (float*)d_out;

  const int PREP_TOT = W1_ELEMS + W2_ELEMS + AM_ELEMS;
  k_prep_all<<<(PREP_TOT + 255) / 256, 256, 0, stream>>>(
      sgc_w, tconv_w, A, M, W1all, W2all, AMall);

  const int GF = NN * 159;           // fused grid
  const int NFC = (TV + 255) >> 8;   // 65
  for (int i = 0; i < 3; ++i) {
    const unsigned short* W1i = W1all + (size_t)i * OO * CC;
    const unsigned short* W2i = W2all + (size_t)i * CC * 576;
    const unsigned short* AMi = AMall + (size_t)i * KK * 1024;
    if (i == 0)
      k_fused_sgc<1><<<GF, 256, 0, stream>>>(
          x, W1i, sgc_b, AMi,
          bnA_g, bnA_b, bnA_m, bnA_v, bufA);
    else
      k_fused_sgc<0><<<GF, 256, 0, stream>>>(
          bufBh, W1i, sgc_b + i * OO, AMi,
          bnA_g + i * CC, bnA_b + i * CC, bnA_m + i * CC, bnA_v + i * CC,
          bufA);
    if (i < 2)
      k_tconv_mfma<0><<<NN * NFC, 256, 0, stream>>>(
          bufA, W2i, tconv_b + i * CC,
          bnB_g + i * CC, bnB_b + i * CC, bnB_m + i * CC, bnB_v + i * CC,
          (void*)bufBh);
    else
      k_tconv_mfma<1><<<NN * NFC, 256, 0, stream>>>(
          bufA, W2i, tconv_b + i * CC,
          bnB_g + i * CC, bnB_b + i * CC, bnB_m + i * CC, bnB_v + i * CC,
          (void*)bufB);
  }
  k_pool<<<NN * CC, 256, 0, stream>>>(bufB, pooled, hmeanv);
  k_head_edge<<<NN, 256, 0, stream>>>(pooled, hmeanv, fc_w, fc_b,
      attbn_g, attbn_b, attbn_m, attbn_v, attconv_w, edgeconv_w,
      edgebn_g, edgebn_b, edgebn_m, edgebn_v, out);
  k_node<<<((size_t)NN * TV + 255) / 256, 256, 0, stream>>>(
      bufB, attbn_g, attbn_b, attbn_m, attbn_v, attconv_w, nodeconv_w,
      nodebn_g, nodebn_b, nodebn_m, nodebn_v, out);
}